// Round 7
// baseline (417.843 us; speedup 1.0000x reference)
//
#include <hip/hip_runtime.h>
#include <hip/hip_bf16.h>

#define NN 50000
#define NE 800000
#define IND 128
#define C 64       // FEAT = HID = OUT
#define NBUCK 196  // coarse buckets of 256 nodes: 196*256 = 50176 >= NN

typedef __hip_bfloat16 bf16;

__device__ __forceinline__ float to_f(float v) { return v; }
__device__ __forceinline__ float to_f(bf16 v)  { return __bfloat162float(v); }

// bf16 <-> fp32 raw helpers (H is stored as ushort bf16 internally)
__device__ __forceinline__ unsigned short f2b(float v) {
    unsigned u = __float_as_uint(v);
    return (unsigned short)((u + 0x7FFFu + ((u >> 16) & 1u)) >> 16);   // RNE
}
__device__ __forceinline__ float b2f(unsigned short u) {
    return __uint_as_float((unsigned)u << 16);
}

// --- dtype detect: float inputs fp32 (flag=1) or bf16 (flag=0)? ------------
__global__ void detect_kernel(const unsigned* __restrict__ xu, int* __restrict__ flag) {
    int lane = threadIdx.x;
    unsigned u  = xu[lane];
    unsigned ex = (u >> 7) & 0xFF;
    int vote = (ex >= 90 && ex <= 144) ? 1 : 0;
#pragma unroll
    for (int off = 32; off; off >>= 1) vote += __shfl_xor(vote, off, 64);
    if (lane == 0) *flag = (vote < 40) ? 1 : 0;
}

// --- degree histogram ------------------------------------------------------
__global__ void count_kernel(const int* __restrict__ tgt, int* __restrict__ cnt) {
    int e = blockIdx.x * blockDim.x + threadIdx.x;
    if (e < NE) atomicAdd(&cnt[tgt[e]], 1);
}

// --- multi-block scan: phase A = per-block (1024 counts) totals ------------
__global__ __launch_bounds__(256) void scanA_kernel(const int4* __restrict__ cnt4,
                                                    int* __restrict__ bsum) {
    __shared__ int ws[4];
    int tid = threadIdx.x;
    int idx = blockIdx.x * 256 + tid;
    int4 v = (idx < NN / 4) ? cnt4[idx] : make_int4(0, 0, 0, 0);
    int s = v.x + v.y + v.z + v.w;
#pragma unroll
    for (int o = 32; o; o >>= 1) s += __shfl_xor(s, o, 64);
    if ((tid & 63) == 0) ws[tid >> 6] = s;
    __syncthreads();
    if (tid == 0) bsum[blockIdx.x] = ws[0] + ws[1] + ws[2] + ws[3];
}

// --- phase C: per-block exclusive scan + base from bsum -> off -------------
__global__ __launch_bounds__(256) void scanC_kernel(const int4* __restrict__ cnt4,
                                                    const int* __restrict__ bsum,
                                                    int* __restrict__ off) {
    __shared__ int wsum[4];
    int tid = threadIdx.x, lane = tid & 63, wv = tid >> 6;
    int b = blockIdx.x;
    int bb = (lane < b) ? bsum[lane] : 0;   // b <= 48 < 64
#pragma unroll
    for (int o = 32; o; o >>= 1) bb += __shfl_xor(bb, o, 64);
    int idx = b * 256 + tid;
    int4 v = (idx < NN / 4) ? cnt4[idx] : make_int4(0, 0, 0, 0);
    int tot = v.x + v.y + v.z + v.w;
    int incl = tot;
#pragma unroll
    for (int d = 1; d < 64; d <<= 1) { int t = __shfl_up(incl, d, 64); if (lane >= d) incl += t; }
    if (lane == 63) wsum[wv] = incl;
    __syncthreads();
    int wbase = 0;
#pragma unroll
    for (int j = 0; j < 4; ++j) wbase += (j < wv) ? wsum[j] : 0;
    int excl = bb + wbase + incl - tot;
    if (idx < NN / 4) {
        off[4 * idx]     = excl;
        off[4 * idx + 1] = excl + v.x;
        off[4 * idx + 2] = excl + v.x + v.y;
        off[4 * idx + 3] = excl + v.x + v.y + v.z;
    }
    if (b == 0 && tid == 0) off[NN] = NE;
}

// --- binA: block-local LDS histogram + clustered append into staging -------
template <typename T>
__device__ __forceinline__ void binA_impl(int* lcnt, int* lbase,
                                          const int* __restrict__ src,
                                          const int* __restrict__ tgt,
                                          const T* __restrict__ ea,
                                          const int* __restrict__ off,
                                          int* __restrict__ ccur,
                                          float4* __restrict__ stg) {
    int tid = threadIdx.x;
    for (int i = tid; i < NBUCK; i += 256) lcnt[i] = 0;
    __syncthreads();
    int e0 = blockIdx.x * 2048;
    float ex[8], ey[8], ez[8];
    unsigned ew[8];
    int eb[8], er[8];
#pragma unroll
    for (int k = 0; k < 8; ++k) {
        int e = e0 + (k << 8) + tid;
        if (e < NE) {
            int t = tgt[e];
            int s = src[e];
            eb[k] = t >> 8;
            ew[k] = ((unsigned)t << 16) | (unsigned)s;
            ex[k] = to_f(ea[e * 3 + 0]);
            ey[k] = to_f(ea[e * 3 + 1]);
            ez[k] = to_f(ea[e * 3 + 2]);
            er[k] = atomicAdd(&lcnt[eb[k]], 1);
        } else eb[k] = -1;
    }
    __syncthreads();
    for (int i = tid; i < NBUCK; i += 256) {
        int c = lcnt[i];
        int g = c ? atomicAdd(&ccur[i], c) : 0;
        lbase[i] = off[i << 8] + g;
    }
    __syncthreads();
#pragma unroll
    for (int k = 0; k < 8; ++k) {
        if (eb[k] >= 0) {
            float4 r;
            r.x = ex[k]; r.y = ey[k]; r.z = ez[k];
            r.w = __uint_as_float(ew[k]);
            stg[lbase[eb[k]] + er[k]] = r;
        }
    }
}

__global__ __launch_bounds__(256) void binA_kernel(const int* __restrict__ src,
                                                   const int* __restrict__ tgt,
                                                   const void* ea,
                                                   const int* __restrict__ off,
                                                   const int* __restrict__ flagp,
                                                   int* __restrict__ ccur,
                                                   float4* __restrict__ stg) {
    __shared__ int lcnt[NBUCK];
    __shared__ int lbase[NBUCK];
    if (*flagp) binA_impl<float>(lcnt, lbase, src, tgt, (const float*)ea, off, ccur, stg);
    else        binA_impl<bf16>(lcnt, lbase, src, tgt, (const bf16*)ea, off, ccur, stg);
}

// --- binB: one block per bucket; contiguous read, LDS-ranked local scatter -
__global__ __launch_bounds__(256) void binB_kernel(const float4* __restrict__ stg,
                                                   const int* __restrict__ off,
                                                   float4* __restrict__ edge) {
    __shared__ int lfill[256];
    __shared__ int loff[257];
    int tid = threadIdx.x;
    int n0 = blockIdx.x << 8;
    int nn = min(256, NN - n0);
    for (int i = tid; i < nn; i += 256) lfill[i] = 0;
    for (int i = tid; i <= nn; i += 256) loff[i] = off[n0 + i];
    __syncthreads();
    int cb = loff[0], ce = loff[nn];
    for (int i = cb + tid; i < ce; i += 256) {
        float4 r = stg[i];
        unsigned w = __float_as_uint(r.w);
        int l = (int)(w >> 16) & 255;           // t - n0
        int rk = atomicAdd(&lfill[l], 1);       // LDS atomic
        r.w = __uint_as_float(w & 0xFFFFu);     // final record keeps src only
        edge[loff[l] + rk] = r;
    }
}

// --- linear_pre: 64 rows/block, 4x4 register tile; H stored bf16 -----------
// (round-2 form: scalar weight loads — vectorized form spilled to scratch)
template <typename T>
__device__ __forceinline__ void pre_impl(float (*Xl)[132], const T* __restrict__ x,
                                         const T* __restrict__ w, const T* __restrict__ b,
                                         unsigned short* __restrict__ h) {
    int tid = threadIdx.x;
    int nb  = blockIdx.x * 64;
    if constexpr (sizeof(T) == 2) {
        const ushort4* xg = (const ushort4*)(x + (size_t)nb * IND);
        for (int j = tid; j < 64 * 32; j += 256) {
            int row = j >> 5, kk = (j & 31) * 4;
            ushort4 u = (nb + row < NN) ? xg[j] : make_ushort4(0, 0, 0, 0);
            Xl[row][kk]     = b2f(u.x);
            Xl[row][kk + 1] = b2f(u.y);
            Xl[row][kk + 2] = b2f(u.z);
            Xl[row][kk + 3] = b2f(u.w);
        }
    } else {
        const float4* xg = (const float4*)(x + (size_t)nb * IND);
        for (int j = tid; j < 64 * 32; j += 256) {
            int row = j >> 5, kk = (j & 31) * 4;
            float4 v = (nb + row < NN) ? xg[j] : make_float4(0.f, 0.f, 0.f, 0.f);
            Xl[row][kk] = v.x; Xl[row][kk + 1] = v.y; Xl[row][kk + 2] = v.z; Xl[row][kk + 3] = v.w;
        }
    }
    __syncthreads();
    int tx = tid & 15, ty = tid >> 4, c0 = tx * 4;
    float acc[4][4];
#pragma unroll
    for (int r = 0; r < 4; ++r)
#pragma unroll
        for (int j = 0; j < 4; ++j) acc[r][j] = to_f(b[c0 + j]);
    for (int k = 0; k < IND; k += 4) {
#pragma unroll
        for (int kk = 0; kk < 4; ++kk) {
            float wv[4];
#pragma unroll
            for (int j = 0; j < 4; ++j) wv[j] = to_f(w[(k + kk) * C + c0 + j]);
#pragma unroll
            for (int r = 0; r < 4; ++r) {
                float sv = Xl[ty + 16 * r][k + kk];
#pragma unroll
                for (int j = 0; j < 4; ++j) acc[r][j] += sv * wv[j];
            }
        }
    }
#pragma unroll
    for (int r = 0; r < 4; ++r) {
        int row = nb + ty + 16 * r;
        if (row < NN) {
            ushort4 uv = make_ushort4(f2b(acc[r][0]), f2b(acc[r][1]), f2b(acc[r][2]), f2b(acc[r][3]));
            *(ushort4*)(h + (size_t)row * C + c0) = uv;
        }
    }
}

__global__ __launch_bounds__(256) void pre_kernel(const void* x, const void* w, const void* b,
                                                  const int* __restrict__ flagp,
                                                  unsigned short* __restrict__ h) {
    __shared__ float Xl[64][132];
    if (*flagp) pre_impl<float>(Xl, (const float*)x, (const float*)w, (const float*)b, h);
    else        pre_impl<bf16>(Xl, (const bf16*)x, (const bf16*)w, (const bf16*)b, h);
}

// --- aggregation: one wave/node, software-pipelined, bf16 h gathers --------
__global__ __launch_bounds__(256) void agg_kernel(const unsigned short* __restrict__ hb,
                                                  const float4* __restrict__ edge,
                                                  const int* __restrict__ off,
                                                  float* __restrict__ s) {
    int f = threadIdx.x & 63;
    int n = blockIdx.x * 4 + (threadIdx.x >> 6);
    int beg = __builtin_amdgcn_readfirstlane(off[n]);
    int end = __builtin_amdgcn_readfirstlane(off[n + 1]);
    float a0 = 0.f, a1 = 0.f, a2 = 0.f;
    int e = beg;
    int m4 = beg + ((end - beg) & ~3);
    if (e < m4) {
        float4 c0 = edge[e], c1 = edge[e + 1], c2 = edge[e + 2], c3 = edge[e + 3];
        e += 4;
        for (; e < m4; e += 4) {
            float h0 = b2f(hb[(__float_as_int(c0.w) << 6) + f]);
            float h1 = b2f(hb[(__float_as_int(c1.w) << 6) + f]);
            float h2 = b2f(hb[(__float_as_int(c2.w) << 6) + f]);
            float h3 = b2f(hb[(__float_as_int(c3.w) << 6) + f]);
            float4 n0 = edge[e], n1 = edge[e + 1], n2 = edge[e + 2], n3 = edge[e + 3];
            a0 += c0.x * h0; a1 += c0.y * h0; a2 += c0.z * h0;
            a0 += c1.x * h1; a1 += c1.y * h1; a2 += c1.z * h1;
            a0 += c2.x * h2; a1 += c2.y * h2; a2 += c2.z * h2;
            a0 += c3.x * h3; a1 += c3.y * h3; a2 += c3.z * h3;
            c0 = n0; c1 = n1; c2 = n2; c3 = n3;
        }
        float h0 = b2f(hb[(__float_as_int(c0.w) << 6) + f]);
        float h1 = b2f(hb[(__float_as_int(c1.w) << 6) + f]);
        float h2 = b2f(hb[(__float_as_int(c2.w) << 6) + f]);
        float h3 = b2f(hb[(__float_as_int(c3.w) << 6) + f]);
        a0 += c0.x * h0; a1 += c0.y * h0; a2 += c0.z * h0;
        a0 += c1.x * h1; a1 += c1.y * h1; a2 += c1.z * h1;
        a0 += c2.x * h2; a1 += c2.y * h2; a2 += c2.z * h2;
        a0 += c3.x * h3; a1 += c3.y * h3; a2 += c3.z * h3;
    }
    for (; e < end; ++e) {
        float4 r = edge[e];
        float hv = b2f(hb[(__float_as_int(r.w) << 6) + f]);
        a0 += r.x * hv; a1 += r.y * hv; a2 += r.z * hv;
    }
    float iv = 1.0f / fmaxf((float)(end - beg), 1.0f);
    float* so = s + n * 192;
    so[f] = a0 * iv; so[64 + f] = a1 * iv; so[128 + f] = a2 * iv;
}

// --- dense: out = S @ W + b; 64 rows/block, 512 threads, 2x4 tile ----------
// 8 waves/block x 3 blocks/CU = 24 waves/CU (was 12) — occupancy fix.
// MODE 0: relu -> hout (bf16); MODE 1: L2-normalize -> out (T)
template <typename T, int MODE>
__device__ __forceinline__ void gemm_impl(float (*Sl)[196], const float* __restrict__ s,
                                          const T* __restrict__ w, const T* __restrict__ b,
                                          unsigned short* __restrict__ hout, T* __restrict__ out) {
    int tid = threadIdx.x;
    int nb  = blockIdx.x * 64;
    const float4* sg = (const float4*)(s + (size_t)nb * 192);
    for (int j = tid; j < 64 * 48; j += 512) {
        int row = j / 48, kk = (j % 48) * 4;
        float4 v = (nb + row < NN) ? sg[j] : make_float4(0.f, 0.f, 0.f, 0.f);
        Sl[row][kk] = v.x; Sl[row][kk + 1] = v.y; Sl[row][kk + 2] = v.z; Sl[row][kk + 3] = v.w;
    }
    __syncthreads();
    int tx = tid & 15, ty = tid >> 4, c0 = tx * 4;   // ty in [0,32)
    float acc[2][4];
#pragma unroll
    for (int r = 0; r < 2; ++r)
#pragma unroll
        for (int j = 0; j < 4; ++j) acc[r][j] = to_f(b[c0 + j]);
    for (int k = 0; k < 192; k += 4) {
        float wr[4][4];   // wr[kk][j]
        if constexpr (sizeof(T) == 4) {
#pragma unroll
            for (int kk = 0; kk < 4; ++kk) {
                float4 wq = *(const float4*)((const float*)w + (k + kk) * C + c0);
                wr[kk][0] = wq.x; wr[kk][1] = wq.y; wr[kk][2] = wq.z; wr[kk][3] = wq.w;
            }
        } else {
#pragma unroll
            for (int kk = 0; kk < 4; ++kk) {
                ushort4 uq = *(const ushort4*)((const unsigned short*)w + (k + kk) * C + c0);
                wr[kk][0] = b2f(uq.x); wr[kk][1] = b2f(uq.y);
                wr[kk][2] = b2f(uq.z); wr[kk][3] = b2f(uq.w);
            }
        }
#pragma unroll
        for (int r = 0; r < 2; ++r) {
            float4 sv = *(const float4*)&Sl[ty + 32 * r][k];
#pragma unroll
            for (int j = 0; j < 4; ++j)
                acc[r][j] += sv.x * wr[0][j] + sv.y * wr[1][j] + sv.z * wr[2][j] + sv.w * wr[3][j];
        }
    }
#pragma unroll
    for (int r = 0; r < 2; ++r) {
        int row = nb + ty + 32 * r;
        if constexpr (MODE == 0) {
            if (row < NN) {
                ushort4 uv = make_ushort4(f2b(fmaxf(acc[r][0], 0.f)), f2b(fmaxf(acc[r][1], 0.f)),
                                          f2b(fmaxf(acc[r][2], 0.f)), f2b(fmaxf(acc[r][3], 0.f)));
                *(ushort4*)(hout + (size_t)row * C + c0) = uv;
            }
        } else {
            float sq = acc[r][0] * acc[r][0] + acc[r][1] * acc[r][1]
                     + acc[r][2] * acc[r][2] + acc[r][3] * acc[r][3];
#pragma unroll
            for (int o = 1; o < 16; o <<= 1) sq += __shfl_xor(sq, o, 64);
            float innorm = 1.0f / fmaxf(sqrtf(sq), 1e-12f);
            if (row < NN) {
#pragma unroll
                for (int j = 0; j < 4; ++j) {
                    float rv = acc[r][j] * innorm;
                    if constexpr (sizeof(T) == 2) out[(size_t)row * C + c0 + j] = __float2bfloat16(rv);
                    else                          out[(size_t)row * C + c0 + j] = rv;
                }
            }
        }
    }
}

__global__ __launch_bounds__(512) void gemm_relu(const float* __restrict__ s, const void* w,
                                                 const void* b, const int* __restrict__ flagp,
                                                 unsigned short* __restrict__ hout) {
    __shared__ float Sl[64][196];
    if (*flagp) gemm_impl<float, 0>(Sl, s, (const float*)w, (const float*)b, hout, (float*)nullptr);
    else        gemm_impl<bf16, 0>(Sl, s, (const bf16*)w, (const bf16*)b, hout, (bf16*)nullptr);
}

__global__ __launch_bounds__(512) void gemm_norm(const float* __restrict__ s, const void* w,
                                                 const void* b, const int* __restrict__ flagp,
                                                 void* out) {
    __shared__ float Sl[64][196];
    if (*flagp) gemm_impl<float, 1>(Sl, s, (const float*)w, (const float*)b, nullptr, (float*)out);
    else        gemm_impl<bf16, 1>(Sl, s, (const bf16*)w, (const bf16*)b, nullptr, (bf16*)out);
}

extern "C" void kernel_launch(void* const* d_in, const int* in_sizes, int n_in,
                              void* d_out, int out_size, void* d_ws, size_t ws_size,
                              hipStream_t stream) {
    const void* x     = d_in[0];
    const int*  ei    = (const int*)d_in[1];
    const void* ea    = d_in[2];
    const void* pre_w = d_in[3];
    const void* pre_b = d_in[4];
    const void* W[3]  = {d_in[5], d_in[7], d_in[9]};
    const void* B[3]  = {d_in[6], d_in[8], d_in[10]};
    const int* src = ei;
    const int* tgt = ei + NE;

    // ws layout: EDGE f4[NE] | S f32[NN*192] (staging STG overlays S)
    //            | H bf16[NN*64] | CNT[NN] | CCUR[256] | OFF[NN+8] | BSUM[64] | FLAG
    float4*         EDGE = (float4*)d_ws;                            // 12.8 MB
    float*          S    = (float*)(EDGE + NE);                      // 38.4 MB
    float4*         STG  = (float4*)S;                               // overlay (12.8 MB)
    unsigned short* H    = (unsigned short*)(S + (size_t)NN * 192);  // 6.4 MB
    int*            CNT  = (int*)(H + (size_t)NN * C);               // 16B-aligned
    int*            CCUR = CNT + NN;
    int*            OFF  = CCUR + 256;
    int*            BSUM = OFF + NN + 8;
    int*            FLAG = BSUM + 64;

    detect_kernel<<<1, 64, 0, stream>>>((const unsigned*)x, FLAG);
    hipMemsetAsync(CNT, 0, (NN + 256) * sizeof(int), stream);   // CNT + CCUR
    count_kernel<<<(NE + 255) / 256, 256, 0, stream>>>(tgt, CNT);
    scanA_kernel<<<(NN / 4 + 255) / 256, 256, 0, stream>>>((const int4*)CNT, BSUM);
    scanC_kernel<<<(NN / 4 + 255) / 256, 256, 0, stream>>>((const int4*)CNT, BSUM, OFF);
    binA_kernel<<<(NE + 2047) / 2048, 256, 0, stream>>>(src, tgt, ea, OFF, FLAG, CCUR, STG);
    binB_kernel<<<NBUCK, 256, 0, stream>>>(STG, OFF, EDGE);
    pre_kernel<<<(NN + 63) / 64, 256, 0, stream>>>(x, pre_w, pre_b, FLAG, H);

    int nblk = (NN + 63) / 64;
    for (int l = 0; l < 3; ++l) {
        agg_kernel<<<NN / 4, 256, 0, stream>>>(H, EDGE, OFF, S);
        if (l < 2)
            gemm_relu<<<nblk, 512, 0, stream>>>(S, W[l], B[l], FLAG, H);
        else
            gemm_norm<<<nblk, 512, 0, stream>>>(S, W[l], B[l], FLAG, d_out);
    }
}

// Round 8
// 393.045 us; speedup vs baseline: 1.0631x; 1.0631x over previous
//
#include <hip/hip_runtime.h>
#include <hip/hip_bf16.h>

#define NN 50000
#define NE 800000
#define IND 128
#define C 64       // FEAT = HID = OUT
#define NBUCK 196  // coarse buckets of 256 nodes: 196*256 = 50176 >= NN

typedef __hip_bfloat16 bf16;

__device__ __forceinline__ float to_f(float v) { return v; }
__device__ __forceinline__ float to_f(bf16 v)  { return __bfloat162float(v); }

// bf16 <-> fp32 raw helpers (H is stored as ushort bf16 internally)
__device__ __forceinline__ unsigned short f2b(float v) {
    unsigned u = __float_as_uint(v);
    return (unsigned short)((u + 0x7FFFu + ((u >> 16) & 1u)) >> 16);   // RNE
}
__device__ __forceinline__ float b2f(unsigned short u) {
    return __uint_as_float((unsigned)u << 16);
}

// --- dtype detect: float inputs fp32 (flag=1) or bf16 (flag=0)? ------------
__global__ void detect_kernel(const unsigned* __restrict__ xu, int* __restrict__ flag) {
    int lane = threadIdx.x;
    unsigned u  = xu[lane];
    unsigned ex = (u >> 7) & 0xFF;
    int vote = (ex >= 90 && ex <= 144) ? 1 : 0;
#pragma unroll
    for (int off = 32; off; off >>= 1) vote += __shfl_xor(vote, off, 64);
    if (lane == 0) *flag = (vote < 40) ? 1 : 0;
}

// --- degree histogram ------------------------------------------------------
__global__ void count_kernel(const int* __restrict__ tgt, int* __restrict__ cnt) {
    int e = blockIdx.x * blockDim.x + threadIdx.x;
    if (e < NE) atomicAdd(&cnt[tgt[e]], 1);
}

// --- multi-block scan: phase A = per-block (1024 counts) totals ------------
__global__ __launch_bounds__(256) void scanA_kernel(const int4* __restrict__ cnt4,
                                                    int* __restrict__ bsum) {
    __shared__ int ws[4];
    int tid = threadIdx.x;
    int idx = blockIdx.x * 256 + tid;
    int4 v = (idx < NN / 4) ? cnt4[idx] : make_int4(0, 0, 0, 0);
    int s = v.x + v.y + v.z + v.w;
#pragma unroll
    for (int o = 32; o; o >>= 1) s += __shfl_xor(s, o, 64);
    if ((tid & 63) == 0) ws[tid >> 6] = s;
    __syncthreads();
    if (tid == 0) bsum[blockIdx.x] = ws[0] + ws[1] + ws[2] + ws[3];
}

// --- phase C: per-block exclusive scan + base from bsum -> off -------------
__global__ __launch_bounds__(256) void scanC_kernel(const int4* __restrict__ cnt4,
                                                    const int* __restrict__ bsum,
                                                    int* __restrict__ off) {
    __shared__ int wsum[4];
    int tid = threadIdx.x, lane = tid & 63, wv = tid >> 6;
    int b = blockIdx.x;
    int bb = (lane < b) ? bsum[lane] : 0;   // b <= 48 < 64
#pragma unroll
    for (int o = 32; o; o >>= 1) bb += __shfl_xor(bb, o, 64);
    int idx = b * 256 + tid;
    int4 v = (idx < NN / 4) ? cnt4[idx] : make_int4(0, 0, 0, 0);
    int tot = v.x + v.y + v.z + v.w;
    int incl = tot;
#pragma unroll
    for (int d = 1; d < 64; d <<= 1) { int t = __shfl_up(incl, d, 64); if (lane >= d) incl += t; }
    if (lane == 63) wsum[wv] = incl;
    __syncthreads();
    int wbase = 0;
#pragma unroll
    for (int j = 0; j < 4; ++j) wbase += (j < wv) ? wsum[j] : 0;
    int excl = bb + wbase + incl - tot;
    if (idx < NN / 4) {
        off[4 * idx]     = excl;
        off[4 * idx + 1] = excl + v.x;
        off[4 * idx + 2] = excl + v.x + v.y;
        off[4 * idx + 3] = excl + v.x + v.y + v.z;
    }
    if (b == 0 && tid == 0) off[NN] = NE;
}

// --- binA: block-local LDS histogram + clustered append into staging -------
template <typename T>
__device__ __forceinline__ void binA_impl(int* lcnt, int* lbase,
                                          const int* __restrict__ src,
                                          const int* __restrict__ tgt,
                                          const T* __restrict__ ea,
                                          const int* __restrict__ off,
                                          int* __restrict__ ccur,
                                          float4* __restrict__ stg) {
    int tid = threadIdx.x;
    for (int i = tid; i < NBUCK; i += 256) lcnt[i] = 0;
    __syncthreads();
    int e0 = blockIdx.x * 2048;
    float ex[8], ey[8], ez[8];
    unsigned ew[8];
    int eb[8], er[8];
#pragma unroll
    for (int k = 0; k < 8; ++k) {
        int e = e0 + (k << 8) + tid;
        if (e < NE) {
            int t = tgt[e];
            int s = src[e];
            eb[k] = t >> 8;
            ew[k] = ((unsigned)t << 16) | (unsigned)s;
            ex[k] = to_f(ea[e * 3 + 0]);
            ey[k] = to_f(ea[e * 3 + 1]);
            ez[k] = to_f(ea[e * 3 + 2]);
            er[k] = atomicAdd(&lcnt[eb[k]], 1);
        } else eb[k] = -1;
    }
    __syncthreads();
    for (int i = tid; i < NBUCK; i += 256) {
        int c = lcnt[i];
        int g = c ? atomicAdd(&ccur[i], c) : 0;
        lbase[i] = off[i << 8] + g;
    }
    __syncthreads();
#pragma unroll
    for (int k = 0; k < 8; ++k) {
        if (eb[k] >= 0) {
            float4 r;
            r.x = ex[k]; r.y = ey[k]; r.z = ez[k];
            r.w = __uint_as_float(ew[k]);
            stg[lbase[eb[k]] + er[k]] = r;
        }
    }
}

__global__ __launch_bounds__(256) void binA_kernel(const int* __restrict__ src,
                                                   const int* __restrict__ tgt,
                                                   const void* ea,
                                                   const int* __restrict__ off,
                                                   const int* __restrict__ flagp,
                                                   int* __restrict__ ccur,
                                                   float4* __restrict__ stg) {
    __shared__ int lcnt[NBUCK];
    __shared__ int lbase[NBUCK];
    if (*flagp) binA_impl<float>(lcnt, lbase, src, tgt, (const float*)ea, off, ccur, stg);
    else        binA_impl<bf16>(lcnt, lbase, src, tgt, (const bf16*)ea, off, ccur, stg);
}

// --- binB: one block per bucket; contiguous read, LDS-ranked local scatter -
__global__ __launch_bounds__(256) void binB_kernel(const float4* __restrict__ stg,
                                                   const int* __restrict__ off,
                                                   float4* __restrict__ edge) {
    __shared__ int lfill[256];
    __shared__ int loff[257];
    int tid = threadIdx.x;
    int n0 = blockIdx.x << 8;
    int nn = min(256, NN - n0);
    for (int i = tid; i < nn; i += 256) lfill[i] = 0;
    for (int i = tid; i <= nn; i += 256) loff[i] = off[n0 + i];
    __syncthreads();
    int cb = loff[0], ce = loff[nn];
    for (int i = cb + tid; i < ce; i += 256) {
        float4 r = stg[i];
        unsigned w = __float_as_uint(r.w);
        int l = (int)(w >> 16) & 255;           // t - n0
        int rk = atomicAdd(&lfill[l], 1);       // LDS atomic
        r.w = __uint_as_float(w & 0xFFFFu);     // final record keeps src only
        edge[loff[l] + rk] = r;
    }
}

// --- linear_pre: 64 rows/block, 4x4 register tile; H stored bf16 -----------
// (round-2 form: scalar weight loads — vectorized form spilled to scratch)
template <typename T>
__device__ __forceinline__ void pre_impl(float (*Xl)[132], const T* __restrict__ x,
                                         const T* __restrict__ w, const T* __restrict__ b,
                                         unsigned short* __restrict__ h) {
    int tid = threadIdx.x;
    int nb  = blockIdx.x * 64;
    if constexpr (sizeof(T) == 2) {
        const ushort4* xg = (const ushort4*)(x + (size_t)nb * IND);
        for (int j = tid; j < 64 * 32; j += 256) {
            int row = j >> 5, kk = (j & 31) * 4;
            ushort4 u = (nb + row < NN) ? xg[j] : make_ushort4(0, 0, 0, 0);
            Xl[row][kk]     = b2f(u.x);
            Xl[row][kk + 1] = b2f(u.y);
            Xl[row][kk + 2] = b2f(u.z);
            Xl[row][kk + 3] = b2f(u.w);
        }
    } else {
        const float4* xg = (const float4*)(x + (size_t)nb * IND);
        for (int j = tid; j < 64 * 32; j += 256) {
            int row = j >> 5, kk = (j & 31) * 4;
            float4 v = (nb + row < NN) ? xg[j] : make_float4(0.f, 0.f, 0.f, 0.f);
            Xl[row][kk] = v.x; Xl[row][kk + 1] = v.y; Xl[row][kk + 2] = v.z; Xl[row][kk + 3] = v.w;
        }
    }
    __syncthreads();
    int tx = tid & 15, ty = tid >> 4, c0 = tx * 4;
    float acc[4][4];
#pragma unroll
    for (int r = 0; r < 4; ++r)
#pragma unroll
        for (int j = 0; j < 4; ++j) acc[r][j] = to_f(b[c0 + j]);
    for (int k = 0; k < IND; k += 4) {
#pragma unroll
        for (int kk = 0; kk < 4; ++kk) {
            float wv[4];
#pragma unroll
            for (int j = 0; j < 4; ++j) wv[j] = to_f(w[(k + kk) * C + c0 + j]);
#pragma unroll
            for (int r = 0; r < 4; ++r) {
                float sv = Xl[ty + 16 * r][k + kk];
#pragma unroll
                for (int j = 0; j < 4; ++j) acc[r][j] += sv * wv[j];
            }
        }
    }
#pragma unroll
    for (int r = 0; r < 4; ++r) {
        int row = nb + ty + 16 * r;
        if (row < NN) {
            ushort4 uv = make_ushort4(f2b(acc[r][0]), f2b(acc[r][1]), f2b(acc[r][2]), f2b(acc[r][3]));
            *(ushort4*)(h + (size_t)row * C + c0) = uv;
        }
    }
}

__global__ __launch_bounds__(256) void pre_kernel(const void* x, const void* w, const void* b,
                                                  const int* __restrict__ flagp,
                                                  unsigned short* __restrict__ h) {
    __shared__ float Xl[64][132];
    if (*flagp) pre_impl<float>(Xl, (const float*)x, (const float*)w, (const float*)b, h);
    else        pre_impl<bf16>(Xl, (const bf16*)x, (const bf16*)w, (const bf16*)b, h);
}

// --- aggregation: one wave/node, software-pipelined, bf16 h gathers --------
__global__ __launch_bounds__(256) void agg_kernel(const unsigned short* __restrict__ hb,
                                                  const float4* __restrict__ edge,
                                                  const int* __restrict__ off,
                                                  float* __restrict__ s) {
    int f = threadIdx.x & 63;
    int n = blockIdx.x * 4 + (threadIdx.x >> 6);
    int beg = __builtin_amdgcn_readfirstlane(off[n]);
    int end = __builtin_amdgcn_readfirstlane(off[n + 1]);
    float a0 = 0.f, a1 = 0.f, a2 = 0.f;
    int e = beg;
    int m4 = beg + ((end - beg) & ~3);
    if (e < m4) {
        float4 c0 = edge[e], c1 = edge[e + 1], c2 = edge[e + 2], c3 = edge[e + 3];
        e += 4;
        for (; e < m4; e += 4) {
            float h0 = b2f(hb[(__float_as_int(c0.w) << 6) + f]);
            float h1 = b2f(hb[(__float_as_int(c1.w) << 6) + f]);
            float h2 = b2f(hb[(__float_as_int(c2.w) << 6) + f]);
            float h3 = b2f(hb[(__float_as_int(c3.w) << 6) + f]);
            float4 n0 = edge[e], n1 = edge[e + 1], n2 = edge[e + 2], n3 = edge[e + 3];
            a0 += c0.x * h0; a1 += c0.y * h0; a2 += c0.z * h0;
            a0 += c1.x * h1; a1 += c1.y * h1; a2 += c1.z * h1;
            a0 += c2.x * h2; a1 += c2.y * h2; a2 += c2.z * h2;
            a0 += c3.x * h3; a1 += c3.y * h3; a2 += c3.z * h3;
            c0 = n0; c1 = n1; c2 = n2; c3 = n3;
        }
        float h0 = b2f(hb[(__float_as_int(c0.w) << 6) + f]);
        float h1 = b2f(hb[(__float_as_int(c1.w) << 6) + f]);
        float h2 = b2f(hb[(__float_as_int(c2.w) << 6) + f]);
        float h3 = b2f(hb[(__float_as_int(c3.w) << 6) + f]);
        a0 += c0.x * h0; a1 += c0.y * h0; a2 += c0.z * h0;
        a0 += c1.x * h1; a1 += c1.y * h1; a2 += c1.z * h1;
        a0 += c2.x * h2; a1 += c2.y * h2; a2 += c2.z * h2;
        a0 += c3.x * h3; a1 += c3.y * h3; a2 += c3.z * h3;
    }
    for (; e < end; ++e) {
        float4 r = edge[e];
        float hv = b2f(hb[(__float_as_int(r.w) << 6) + f]);
        a0 += r.x * hv; a1 += r.y * hv; a2 += r.z * hv;
    }
    float iv = 1.0f / fmaxf((float)(end - beg), 1.0f);
    float* so = s + n * 192;
    so[f] = a0 * iv; so[64 + f] = a1 * iv; so[128 + f] = a2 * iv;
}

// --- dense: out = S @ W + b; W staged in LDS (48 KB), S 16-row tiles -------
// Inner loop is pure LDS + FMA: no global traffic, no redundant W streams.
// MODE 0: relu -> hout (bf16); MODE 1: L2-normalize -> out (T)
template <typename T, int MODE>
__device__ __forceinline__ void gemm_impl(float* Wl, float (*Sl)[196],
                                          const float* __restrict__ s,
                                          const T* __restrict__ w, const T* __restrict__ b,
                                          unsigned short* __restrict__ hout, T* __restrict__ out) {
    int tid = threadIdx.x;
    int nb  = blockIdx.x * 16;
    // stage W [192][64] -> LDS (fp32), linear copy
    if constexpr (sizeof(T) == 4) {
        const float4* wg = (const float4*)w;
        for (int j = tid; j < 192 * 16; j += 256) {   // 3072 float4
            float4 v = wg[j];
            *(float4*)&Wl[j * 4] = v;
        }
    } else {
        const ushort4* wg = (const ushort4*)w;
        for (int j = tid; j < 192 * 16; j += 256) {   // 3072 ushort4
            ushort4 u = wg[j];
            float4 v = make_float4(b2f(u.x), b2f(u.y), b2f(u.z), b2f(u.w));
            *(float4*)&Wl[j * 4] = v;
        }
    }
    // stage S tile [16][192]
    const float4* sg = (const float4*)(s + (size_t)nb * 192);
    for (int j = tid; j < 16 * 48; j += 256) {
        int row = j / 48, kk = (j % 48) * 4;
        float4 v = sg[j];
        *(float4*)&Sl[row][kk] = v;
    }
    __syncthreads();
    int tx = tid & 15, ty = tid >> 4, c0 = tx * 4;   // ty in [0,16): one row/thread
    float acc[4];
#pragma unroll
    for (int j = 0; j < 4; ++j) acc[j] = to_f(b[c0 + j]);
    for (int k = 0; k < 192; k += 4) {
        float4 sv = *(const float4*)&Sl[ty][k];
        float4 w0 = *(const float4*)&Wl[(k + 0) * 64 + c0];
        float4 w1 = *(const float4*)&Wl[(k + 1) * 64 + c0];
        float4 w2 = *(const float4*)&Wl[(k + 2) * 64 + c0];
        float4 w3 = *(const float4*)&Wl[(k + 3) * 64 + c0];
        acc[0] += sv.x * w0.x + sv.y * w1.x + sv.z * w2.x + sv.w * w3.x;
        acc[1] += sv.x * w0.y + sv.y * w1.y + sv.z * w2.y + sv.w * w3.y;
        acc[2] += sv.x * w0.z + sv.y * w1.z + sv.z * w2.z + sv.w * w3.z;
        acc[3] += sv.x * w0.w + sv.y * w1.w + sv.z * w2.w + sv.w * w3.w;
    }
    int row = nb + ty;
    if constexpr (MODE == 0) {
        if (row < NN) {
            ushort4 uv = make_ushort4(f2b(fmaxf(acc[0], 0.f)), f2b(fmaxf(acc[1], 0.f)),
                                      f2b(fmaxf(acc[2], 0.f)), f2b(fmaxf(acc[3], 0.f)));
            *(ushort4*)(hout + (size_t)row * C + c0) = uv;
        }
    } else {
        float sq = acc[0] * acc[0] + acc[1] * acc[1] + acc[2] * acc[2] + acc[3] * acc[3];
#pragma unroll
        for (int o = 1; o < 16; o <<= 1) sq += __shfl_xor(sq, o, 64);
        float innorm = 1.0f / fmaxf(sqrtf(sq), 1e-12f);
        if (row < NN) {
#pragma unroll
            for (int j = 0; j < 4; ++j) {
                float rv = acc[j] * innorm;
                if constexpr (sizeof(T) == 2) out[(size_t)row * C + c0 + j] = __float2bfloat16(rv);
                else                          out[(size_t)row * C + c0 + j] = rv;
            }
        }
    }
}

__global__ __launch_bounds__(256) void gemm_relu(const float* __restrict__ s, const void* w,
                                                 const void* b, const int* __restrict__ flagp,
                                                 unsigned short* __restrict__ hout) {
    __shared__ float Wl[192 * 64];
    __shared__ float Sl[16][196];
    if (*flagp) gemm_impl<float, 0>(Wl, Sl, s, (const float*)w, (const float*)b, hout, (float*)nullptr);
    else        gemm_impl<bf16, 0>(Wl, Sl, s, (const bf16*)w, (const bf16*)b, hout, (bf16*)nullptr);
}

__global__ __launch_bounds__(256) void gemm_norm(const float* __restrict__ s, const void* w,
                                                 const void* b, const int* __restrict__ flagp,
                                                 void* out) {
    __shared__ float Wl[192 * 64];
    __shared__ float Sl[16][196];
    if (*flagp) gemm_impl<float, 1>(Wl, Sl, s, (const float*)w, (const float*)b, nullptr, (float*)out);
    else        gemm_impl<bf16, 1>(Wl, Sl, s, (const bf16*)w, (const bf16*)b, nullptr, (bf16*)out);
}

extern "C" void kernel_launch(void* const* d_in, const int* in_sizes, int n_in,
                              void* d_out, int out_size, void* d_ws, size_t ws_size,
                              hipStream_t stream) {
    const void* x     = d_in[0];
    const int*  ei    = (const int*)d_in[1];
    const void* ea    = d_in[2];
    const void* pre_w = d_in[3];
    const void* pre_b = d_in[4];
    const void* W[3]  = {d_in[5], d_in[7], d_in[9]};
    const void* B[3]  = {d_in[6], d_in[8], d_in[10]};
    const int* src = ei;
    const int* tgt = ei + NE;

    // ws layout: EDGE f4[NE] | S f32[NN*192] (staging STG overlays S)
    //            | H bf16[NN*64] | CNT[NN] | CCUR[256] | OFF[NN+8] | BSUM[64] | FLAG
    float4*         EDGE = (float4*)d_ws;                            // 12.8 MB
    float*          S    = (float*)(EDGE + NE);                      // 38.4 MB
    float4*         STG  = (float4*)S;                               // overlay (12.8 MB)
    unsigned short* H    = (unsigned short*)(S + (size_t)NN * 192);  // 6.4 MB
    int*            CNT  = (int*)(H + (size_t)NN * C);               // 16B-aligned
    int*            CCUR = CNT + NN;
    int*            OFF  = CCUR + 256;
    int*            BSUM = OFF + NN + 8;
    int*            FLAG = BSUM + 64;

    detect_kernel<<<1, 64, 0, stream>>>((const unsigned*)x, FLAG);
    hipMemsetAsync(CNT, 0, (NN + 256) * sizeof(int), stream);   // CNT + CCUR
    count_kernel<<<(NE + 255) / 256, 256, 0, stream>>>(tgt, CNT);
    scanA_kernel<<<(NN / 4 + 255) / 256, 256, 0, stream>>>((const int4*)CNT, BSUM);
    scanC_kernel<<<(NN / 4 + 255) / 256, 256, 0, stream>>>((const int4*)CNT, BSUM, OFF);
    binA_kernel<<<(NE + 2047) / 2048, 256, 0, stream>>>(src, tgt, ea, OFF, FLAG, CCUR, STG);
    binB_kernel<<<NBUCK, 256, 0, stream>>>(STG, OFF, EDGE);
    pre_kernel<<<(NN + 63) / 64, 256, 0, stream>>>(x, pre_w, pre_b, FLAG, H);

    int nblk = (NN + 15) / 16;   // 3125
    for (int l = 0; l < 3; ++l) {
        agg_kernel<<<NN / 4, 256, 0, stream>>>(H, EDGE, OFF, S);
        if (l < 2)
            gemm_relu<<<nblk, 256, 0, stream>>>(S, W[l], B[l], FLAG, H);
        else
            gemm_norm<<<nblk, 256, 0, stream>>>(S, W[l], B[l], FLAG, d_out);
    }
}

// Round 9
// 371.930 us; speedup vs baseline: 1.1234x; 1.0568x over previous
//
#include <hip/hip_runtime.h>
#include <hip/hip_bf16.h>

#define NN 50000
#define NE 800000
#define IND 128
#define C 64       // FEAT = HID = OUT
#define NBUCK 196  // coarse buckets of 256 nodes: 196*256 = 50176 >= NN

typedef __hip_bfloat16 bf16;

__device__ __forceinline__ float to_f(float v) { return v; }
__device__ __forceinline__ float to_f(bf16 v)  { return __bfloat162float(v); }

// bf16 <-> fp32 raw helpers (H is stored as ushort bf16 internally)
__device__ __forceinline__ unsigned short f2b(float v) {
    unsigned u = __float_as_uint(v);
    return (unsigned short)((u + 0x7FFFu + ((u >> 16) & 1u)) >> 16);   // RNE
}
__device__ __forceinline__ float b2f(unsigned short u) {
    return __uint_as_float((unsigned)u << 16);
}

// --- dtype detect: float inputs fp32 (flag=1) or bf16 (flag=0)? ------------
__global__ void detect_kernel(const unsigned* __restrict__ xu, int* __restrict__ flag) {
    int lane = threadIdx.x;
    unsigned u  = xu[lane];
    unsigned ex = (u >> 7) & 0xFF;
    int vote = (ex >= 90 && ex <= 144) ? 1 : 0;
#pragma unroll
    for (int off = 32; off; off >>= 1) vote += __shfl_xor(vote, off, 64);
    if (lane == 0) *flag = (vote < 40) ? 1 : 0;
}

// --- degree histogram ------------------------------------------------------
__global__ void count_kernel(const int* __restrict__ tgt, int* __restrict__ cnt) {
    int e = blockIdx.x * blockDim.x + threadIdx.x;
    if (e < NE) atomicAdd(&cnt[tgt[e]], 1);
}

// --- multi-block scan: phase A = per-block (1024 counts) totals ------------
__global__ __launch_bounds__(256) void scanA_kernel(const int4* __restrict__ cnt4,
                                                    int* __restrict__ bsum) {
    __shared__ int ws[4];
    int tid = threadIdx.x;
    int idx = blockIdx.x * 256 + tid;
    int4 v = (idx < NN / 4) ? cnt4[idx] : make_int4(0, 0, 0, 0);
    int s = v.x + v.y + v.z + v.w;
#pragma unroll
    for (int o = 32; o; o >>= 1) s += __shfl_xor(s, o, 64);
    if ((tid & 63) == 0) ws[tid >> 6] = s;
    __syncthreads();
    if (tid == 0) bsum[blockIdx.x] = ws[0] + ws[1] + ws[2] + ws[3];
}

// --- phase C: per-block exclusive scan + base from bsum -> off -------------
__global__ __launch_bounds__(256) void scanC_kernel(const int4* __restrict__ cnt4,
                                                    const int* __restrict__ bsum,
                                                    int* __restrict__ off) {
    __shared__ int wsum[4];
    int tid = threadIdx.x, lane = tid & 63, wv = tid >> 6;
    int b = blockIdx.x;
    int bb = (lane < b) ? bsum[lane] : 0;   // b <= 48 < 64
#pragma unroll
    for (int o = 32; o; o >>= 1) bb += __shfl_xor(bb, o, 64);
    int idx = b * 256 + tid;
    int4 v = (idx < NN / 4) ? cnt4[idx] : make_int4(0, 0, 0, 0);
    int tot = v.x + v.y + v.z + v.w;
    int incl = tot;
#pragma unroll
    for (int d = 1; d < 64; d <<= 1) { int t = __shfl_up(incl, d, 64); if (lane >= d) incl += t; }
    if (lane == 63) wsum[wv] = incl;
    __syncthreads();
    int wbase = 0;
#pragma unroll
    for (int j = 0; j < 4; ++j) wbase += (j < wv) ? wsum[j] : 0;
    int excl = bb + wbase + incl - tot;
    if (idx < NN / 4) {
        off[4 * idx]     = excl;
        off[4 * idx + 1] = excl + v.x;
        off[4 * idx + 2] = excl + v.x + v.y;
        off[4 * idx + 3] = excl + v.x + v.y + v.z;
    }
    if (b == 0 && tid == 0) off[NN] = NE;
}

// --- binA: block-local LDS histogram + clustered append into staging -------
template <typename T>
__device__ __forceinline__ void binA_impl(int* lcnt, int* lbase,
                                          const int* __restrict__ src,
                                          const int* __restrict__ tgt,
                                          const T* __restrict__ ea,
                                          const int* __restrict__ off,
                                          int* __restrict__ ccur,
                                          float4* __restrict__ stg) {
    int tid = threadIdx.x;
    for (int i = tid; i < NBUCK; i += 256) lcnt[i] = 0;
    __syncthreads();
    int e0 = blockIdx.x * 2048;
    float ex[8], ey[8], ez[8];
    unsigned ew[8];
    int eb[8], er[8];
#pragma unroll
    for (int k = 0; k < 8; ++k) {
        int e = e0 + (k << 8) + tid;
        if (e < NE) {
            int t = tgt[e];
            int s = src[e];
            eb[k] = t >> 8;
            ew[k] = ((unsigned)t << 16) | (unsigned)s;
            ex[k] = to_f(ea[e * 3 + 0]);
            ey[k] = to_f(ea[e * 3 + 1]);
            ez[k] = to_f(ea[e * 3 + 2]);
            er[k] = atomicAdd(&lcnt[eb[k]], 1);
        } else eb[k] = -1;
    }
    __syncthreads();
    for (int i = tid; i < NBUCK; i += 256) {
        int c = lcnt[i];
        int g = c ? atomicAdd(&ccur[i], c) : 0;
        lbase[i] = off[i << 8] + g;
    }
    __syncthreads();
#pragma unroll
    for (int k = 0; k < 8; ++k) {
        if (eb[k] >= 0) {
            float4 r;
            r.x = ex[k]; r.y = ey[k]; r.z = ez[k];
            r.w = __uint_as_float(ew[k]);
            stg[lbase[eb[k]] + er[k]] = r;
        }
    }
}

__global__ __launch_bounds__(256) void binA_kernel(const int* __restrict__ src,
                                                   const int* __restrict__ tgt,
                                                   const void* ea,
                                                   const int* __restrict__ off,
                                                   const int* __restrict__ flagp,
                                                   int* __restrict__ ccur,
                                                   float4* __restrict__ stg) {
    __shared__ int lcnt[NBUCK];
    __shared__ int lbase[NBUCK];
    if (*flagp) binA_impl<float>(lcnt, lbase, src, tgt, (const float*)ea, off, ccur, stg);
    else        binA_impl<bf16>(lcnt, lbase, src, tgt, (const bf16*)ea, off, ccur, stg);
}

// --- binB: one block per bucket; contiguous read, LDS-ranked local scatter -
__global__ __launch_bounds__(256) void binB_kernel(const float4* __restrict__ stg,
                                                   const int* __restrict__ off,
                                                   float4* __restrict__ edge) {
    __shared__ int lfill[256];
    __shared__ int loff[257];
    int tid = threadIdx.x;
    int n0 = blockIdx.x << 8;
    int nn = min(256, NN - n0);
    for (int i = tid; i < nn; i += 256) lfill[i] = 0;
    for (int i = tid; i <= nn; i += 256) loff[i] = off[n0 + i];
    __syncthreads();
    int cb = loff[0], ce = loff[nn];
    for (int i = cb + tid; i < ce; i += 256) {
        float4 r = stg[i];
        unsigned w = __float_as_uint(r.w);
        int l = (int)(w >> 16) & 255;           // t - n0
        int rk = atomicAdd(&lfill[l], 1);       // LDS atomic
        r.w = __uint_as_float(w & 0xFFFFu);     // final record keeps src only
        edge[loff[l] + rk] = r;
    }
}

// --- linear_pre: 64 rows/block, 4x4 register tile; H stored bf16 -----------
template <typename T>
__device__ __forceinline__ void pre_impl(float (*Xl)[132], const T* __restrict__ x,
                                         const T* __restrict__ w, const T* __restrict__ b,
                                         unsigned short* __restrict__ h) {
    int tid = threadIdx.x;
    int nb  = blockIdx.x * 64;
    if constexpr (sizeof(T) == 2) {
        const ushort4* xg = (const ushort4*)(x + (size_t)nb * IND);
        for (int j = tid; j < 64 * 32; j += 256) {
            int row = j >> 5, kk = (j & 31) * 4;
            ushort4 u = (nb + row < NN) ? xg[j] : make_ushort4(0, 0, 0, 0);
            Xl[row][kk]     = b2f(u.x);
            Xl[row][kk + 1] = b2f(u.y);
            Xl[row][kk + 2] = b2f(u.z);
            Xl[row][kk + 3] = b2f(u.w);
        }
    } else {
        const float4* xg = (const float4*)(x + (size_t)nb * IND);
        for (int j = tid; j < 64 * 32; j += 256) {
            int row = j >> 5, kk = (j & 31) * 4;
            float4 v = (nb + row < NN) ? xg[j] : make_float4(0.f, 0.f, 0.f, 0.f);
            Xl[row][kk] = v.x; Xl[row][kk + 1] = v.y; Xl[row][kk + 2] = v.z; Xl[row][kk + 3] = v.w;
        }
    }
    __syncthreads();
    int tx = tid & 15, ty = tid >> 4, c0 = tx * 4;
    float acc[4][4];
#pragma unroll
    for (int r = 0; r < 4; ++r)
#pragma unroll
        for (int j = 0; j < 4; ++j) acc[r][j] = to_f(b[c0 + j]);
    for (int k = 0; k < IND; k += 4) {
#pragma unroll
        for (int kk = 0; kk < 4; ++kk) {
            float wv[4];
#pragma unroll
            for (int j = 0; j < 4; ++j) wv[j] = to_f(w[(k + kk) * C + c0 + j]);
#pragma unroll
            for (int r = 0; r < 4; ++r) {
                float sv = Xl[ty + 16 * r][k + kk];
#pragma unroll
                for (int j = 0; j < 4; ++j) acc[r][j] += sv * wv[j];
            }
        }
    }
#pragma unroll
    for (int r = 0; r < 4; ++r) {
        int row = nb + ty + 16 * r;
        if (row < NN) {
            ushort4 uv = make_ushort4(f2b(acc[r][0]), f2b(acc[r][1]), f2b(acc[r][2]), f2b(acc[r][3]));
            *(ushort4*)(h + (size_t)row * C + c0) = uv;
        }
    }
}

__global__ __launch_bounds__(256) void pre_kernel(const void* x, const void* w, const void* b,
                                                  const int* __restrict__ flagp,
                                                  unsigned short* __restrict__ h) {
    __shared__ float Xl[64][132];
    if (*flagp) pre_impl<float>(Xl, (const float*)x, (const float*)w, (const float*)b, h);
    else        pre_impl<bf16>(Xl, (const bf16*)x, (const bf16*)w, (const bf16*)b, h);
}

// --- aggregation: one wave/node, 2-stage pipeline (h prefetched 1 iter ahead)
__global__ __launch_bounds__(256) void agg_kernel(const unsigned short* __restrict__ hb,
                                                  const float4* __restrict__ edge,
                                                  const int* __restrict__ off,
                                                  float* __restrict__ s) {
    int f = threadIdx.x & 63;
    int n = blockIdx.x * 4 + (threadIdx.x >> 6);
    int beg = __builtin_amdgcn_readfirstlane(off[n]);
    int end = __builtin_amdgcn_readfirstlane(off[n + 1]);
    float a0 = 0.f, a1 = 0.f, a2 = 0.f;
    int cnt = end - beg;
    int m4 = beg + (cnt & ~3);
    int e = beg;
    if (beg + 8 <= m4) {
        // prologue: batch c (edges+h), batch d (edges)
        float4 c0 = edge[e],     c1 = edge[e + 1], c2 = edge[e + 2], c3 = edge[e + 3];
        float4 d0 = edge[e + 4], d1 = edge[e + 5], d2 = edge[e + 6], d3 = edge[e + 7];
        float h0 = b2f(hb[(__float_as_int(c0.w) << 6) + f]);
        float h1 = b2f(hb[(__float_as_int(c1.w) << 6) + f]);
        float h2 = b2f(hb[(__float_as_int(c2.w) << 6) + f]);
        float h3 = b2f(hb[(__float_as_int(c3.w) << 6) + f]);
        int e2 = beg + 8;   // next batch to load
        while (e2 < m4) {
            // gather h for d; load next edge batch; FMA batch c (h ready)
            float g0 = b2f(hb[(__float_as_int(d0.w) << 6) + f]);
            float g1 = b2f(hb[(__float_as_int(d1.w) << 6) + f]);
            float g2 = b2f(hb[(__float_as_int(d2.w) << 6) + f]);
            float g3 = b2f(hb[(__float_as_int(d3.w) << 6) + f]);
            float4 n0 = edge[e2], n1 = edge[e2 + 1], n2 = edge[e2 + 2], n3 = edge[e2 + 3];
            a0 += c0.x * h0; a1 += c0.y * h0; a2 += c0.z * h0;
            a0 += c1.x * h1; a1 += c1.y * h1; a2 += c1.z * h1;
            a0 += c2.x * h2; a1 += c2.y * h2; a2 += c2.z * h2;
            a0 += c3.x * h3; a1 += c3.y * h3; a2 += c3.z * h3;
            c0 = d0; c1 = d1; c2 = d2; c3 = d3;
            h0 = g0; h1 = g1; h2 = g2; h3 = g3;
            d0 = n0; d1 = n1; d2 = n2; d3 = n3;
            e2 += 4;
        }
        // epilogue: FMA c (h ready); gather+FMA d
        float g0 = b2f(hb[(__float_as_int(d0.w) << 6) + f]);
        float g1 = b2f(hb[(__float_as_int(d1.w) << 6) + f]);
        float g2 = b2f(hb[(__float_as_int(d2.w) << 6) + f]);
        float g3 = b2f(hb[(__float_as_int(d3.w) << 6) + f]);
        a0 += c0.x * h0; a1 += c0.y * h0; a2 += c0.z * h0;
        a0 += c1.x * h1; a1 += c1.y * h1; a2 += c1.z * h1;
        a0 += c2.x * h2; a1 += c2.y * h2; a2 += c2.z * h2;
        a0 += c3.x * h3; a1 += c3.y * h3; a2 += c3.z * h3;
        a0 += d0.x * g0; a1 += d0.y * g0; a2 += d0.z * g0;
        a0 += d1.x * g1; a1 += d1.y * g1; a2 += d1.z * g1;
        a0 += d2.x * g2; a1 += d2.y * g2; a2 += d2.z * g2;
        a0 += d3.x * g3; a1 += d3.y * g3; a2 += d3.z * g3;
        e = m4;
    } else if (beg + 4 <= m4) {
        float4 c0 = edge[e], c1 = edge[e + 1], c2 = edge[e + 2], c3 = edge[e + 3];
        float h0 = b2f(hb[(__float_as_int(c0.w) << 6) + f]);
        float h1 = b2f(hb[(__float_as_int(c1.w) << 6) + f]);
        float h2 = b2f(hb[(__float_as_int(c2.w) << 6) + f]);
        float h3 = b2f(hb[(__float_as_int(c3.w) << 6) + f]);
        a0 += c0.x * h0; a1 += c0.y * h0; a2 += c0.z * h0;
        a0 += c1.x * h1; a1 += c1.y * h1; a2 += c1.z * h1;
        a0 += c2.x * h2; a1 += c2.y * h2; a2 += c2.z * h2;
        a0 += c3.x * h3; a1 += c3.y * h3; a2 += c3.z * h3;
        e = m4;
    }
    for (; e < end; ++e) {
        float4 r = edge[e];
        float hv = b2f(hb[(__float_as_int(r.w) << 6) + f]);
        a0 += r.x * hv; a1 += r.y * hv; a2 += r.z * hv;
    }
    float iv = 1.0f / fmaxf((float)cnt, 1.0f);
    float* so = s + n * 192;
    so[f] = a0 * iv; so[64 + f] = a1 * iv; so[128 + f] = a2 * iv;
}

// --- dense: out = S @ W + b; round-2 exact form (proven 41.5 us) -----------
// MODE 0: relu -> hout (bf16); MODE 1: L2-normalize -> out (T)
template <typename T, int MODE>
__device__ __forceinline__ void gemm_impl(float (*Sl)[196], const float* __restrict__ s,
                                          const T* __restrict__ w, const T* __restrict__ b,
                                          unsigned short* __restrict__ hout, T* __restrict__ out) {
    int tid = threadIdx.x;
    int nb  = blockIdx.x * 64;
    const float4* sg = (const float4*)(s + (size_t)nb * 192);
    for (int j = tid; j < 64 * 48; j += 256) {
        int row = j / 48, kk = (j % 48) * 4;
        float4 v = (nb + row < NN) ? sg[j] : make_float4(0.f, 0.f, 0.f, 0.f);
        Sl[row][kk] = v.x; Sl[row][kk + 1] = v.y; Sl[row][kk + 2] = v.z; Sl[row][kk + 3] = v.w;
    }
    __syncthreads();
    int tx = tid & 15, ty = tid >> 4, c0 = tx * 4;
    float acc[4][4];
#pragma unroll
    for (int r = 0; r < 4; ++r)
#pragma unroll
        for (int j = 0; j < 4; ++j) acc[r][j] = to_f(b[c0 + j]);
    for (int k = 0; k < 192; k += 4) {
#pragma unroll
        for (int kk = 0; kk < 4; ++kk) {
            float wv[4];
#pragma unroll
            for (int j = 0; j < 4; ++j) wv[j] = to_f(w[(k + kk) * C + c0 + j]);
#pragma unroll
            for (int r = 0; r < 4; ++r) {
                float sv = Sl[ty + 16 * r][k + kk];
#pragma unroll
                for (int j = 0; j < 4; ++j) acc[r][j] += sv * wv[j];
            }
        }
    }
#pragma unroll
    for (int r = 0; r < 4; ++r) {
        int row = nb + ty + 16 * r;
        if constexpr (MODE == 0) {
            if (row < NN) {
                ushort4 uv = make_ushort4(f2b(fmaxf(acc[r][0], 0.f)), f2b(fmaxf(acc[r][1], 0.f)),
                                          f2b(fmaxf(acc[r][2], 0.f)), f2b(fmaxf(acc[r][3], 0.f)));
                *(ushort4*)(hout + (size_t)row * C + c0) = uv;
            }
        } else {
            float sq = acc[r][0] * acc[r][0] + acc[r][1] * acc[r][1]
                     + acc[r][2] * acc[r][2] + acc[r][3] * acc[r][3];
#pragma unroll
            for (int o = 1; o < 16; o <<= 1) sq += __shfl_xor(sq, o, 64);
            float innorm = 1.0f / fmaxf(sqrtf(sq), 1e-12f);
            if (row < NN) {
#pragma unroll
                for (int j = 0; j < 4; ++j) {
                    float rv = acc[r][j] * innorm;
                    if constexpr (sizeof(T) == 2) out[(size_t)row * C + c0 + j] = __float2bfloat16(rv);
                    else                          out[(size_t)row * C + c0 + j] = rv;
                }
            }
        }
    }
}

__global__ __launch_bounds__(256) void gemm_relu(const float* __restrict__ s, const void* w,
                                                 const void* b, const int* __restrict__ flagp,
                                                 unsigned short* __restrict__ hout) {
    __shared__ float Sl[64][196];
    if (*flagp) gemm_impl<float, 0>(Sl, s, (const float*)w, (const float*)b, hout, (float*)nullptr);
    else        gemm_impl<bf16, 0>(Sl, s, (const bf16*)w, (const bf16*)b, hout, (bf16*)nullptr);
}

__global__ __launch_bounds__(256) void gemm_norm(const float* __restrict__ s, const void* w,
                                                 const void* b, const int* __restrict__ flagp,
                                                 void* out) {
    __shared__ float Sl[64][196];
    if (*flagp) gemm_impl<float, 1>(Sl, s, (const float*)w, (const float*)b, nullptr, (float*)out);
    else        gemm_impl<bf16, 1>(Sl, s, (const bf16*)w, (const bf16*)b, nullptr, (bf16*)out);
}

extern "C" void kernel_launch(void* const* d_in, const int* in_sizes, int n_in,
                              void* d_out, int out_size, void* d_ws, size_t ws_size,
                              hipStream_t stream) {
    const void* x     = d_in[0];
    const int*  ei    = (const int*)d_in[1];
    const void* ea    = d_in[2];
    const void* pre_w = d_in[3];
    const void* pre_b = d_in[4];
    const void* W[3]  = {d_in[5], d_in[7], d_in[9]};
    const void* B[3]  = {d_in[6], d_in[8], d_in[10]};
    const int* src = ei;
    const int* tgt = ei + NE;

    // ws layout: EDGE f4[NE] | S f32[NN*192] (staging STG overlays S)
    //            | H bf16[NN*64] | CNT[NN] | CCUR[256] | OFF[NN+8] | BSUM[64] | FLAG
    float4*         EDGE = (float4*)d_ws;                            // 12.8 MB
    float*          S    = (float*)(EDGE + NE);                      // 38.4 MB
    float4*         STG  = (float4*)S;                               // overlay (12.8 MB)
    unsigned short* H    = (unsigned short*)(S + (size_t)NN * 192);  // 6.4 MB
    int*            CNT  = (int*)(H + (size_t)NN * C);               // 16B-aligned
    int*            CCUR = CNT + NN;
    int*            OFF  = CCUR + 256;
    int*            BSUM = OFF + NN + 8;
    int*            FLAG = BSUM + 64;

    detect_kernel<<<1, 64, 0, stream>>>((const unsigned*)x, FLAG);
    hipMemsetAsync(CNT, 0, (NN + 256) * sizeof(int), stream);   // CNT + CCUR
    count_kernel<<<(NE + 255) / 256, 256, 0, stream>>>(tgt, CNT);
    scanA_kernel<<<(NN / 4 + 255) / 256, 256, 0, stream>>>((const int4*)CNT, BSUM);
    scanC_kernel<<<(NN / 4 + 255) / 256, 256, 0, stream>>>((const int4*)CNT, BSUM, OFF);
    binA_kernel<<<(NE + 2047) / 2048, 256, 0, stream>>>(src, tgt, ea, OFF, FLAG, CCUR, STG);
    binB_kernel<<<NBUCK, 256, 0, stream>>>(STG, OFF, EDGE);
    pre_kernel<<<(NN + 63) / 64, 256, 0, stream>>>(x, pre_w, pre_b, FLAG, H);

    int nblk = (NN + 63) / 64;
    for (int l = 0; l < 3; ++l) {
        agg_kernel<<<NN / 4, 256, 0, stream>>>(H, EDGE, OFF, S);
        if (l < 2)
            gemm_relu<<<nblk, 256, 0, stream>>>(S, W[l], B[l], FLAG, H);
        else
            gemm_norm<<<nblk, 256, 0, stream>>>(S, W[l], B[l], FLAG, d_out);
    }
}

// Round 10
// 357.781 us; speedup vs baseline: 1.1679x; 1.0395x over previous
//
#include <hip/hip_runtime.h>
#include <hip/hip_bf16.h>

#define NN 50000
#define NE 800000
#define IND 128
#define C 64       // FEAT = HID = OUT
#define NBUCK 196  // coarse buckets of 256 nodes: 196*256 = 50176 >= NN

typedef __hip_bfloat16 bf16;
typedef __attribute__((ext_vector_type(8))) short s8v;    // 8 bf16 (4 VGPRs)
typedef __attribute__((ext_vector_type(4))) float f4v;    // MFMA C/D

__device__ __forceinline__ float to_f(float v) { return v; }
__device__ __forceinline__ float to_f(bf16 v)  { return __bfloat162float(v); }

// bf16 <-> fp32 raw helpers (H is stored as ushort bf16 internally)
__device__ __forceinline__ unsigned short f2b(float v) {
    unsigned u = __float_as_uint(v);
    return (unsigned short)((u + 0x7FFFu + ((u >> 16) & 1u)) >> 16);   // RNE
}
__device__ __forceinline__ float b2f(unsigned short u) {
    return __uint_as_float((unsigned)u << 16);
}

// --- dtype detect: float inputs fp32 (flag=1) or bf16 (flag=0)? ------------
__global__ void detect_kernel(const unsigned* __restrict__ xu, int* __restrict__ flag) {
    int lane = threadIdx.x;
    unsigned u  = xu[lane];
    unsigned ex = (u >> 7) & 0xFF;
    int vote = (ex >= 90 && ex <= 144) ? 1 : 0;
#pragma unroll
    for (int off = 32; off; off >>= 1) vote += __shfl_xor(vote, off, 64);
    if (lane == 0) *flag = (vote < 40) ? 1 : 0;
}

// --- degree histogram ------------------------------------------------------
__global__ void count_kernel(const int* __restrict__ tgt, int* __restrict__ cnt) {
    int e = blockIdx.x * blockDim.x + threadIdx.x;
    if (e < NE) atomicAdd(&cnt[tgt[e]], 1);
}

// --- multi-block scan: phase A = per-block (1024 counts) totals ------------
__global__ __launch_bounds__(256) void scanA_kernel(const int4* __restrict__ cnt4,
                                                    int* __restrict__ bsum) {
    __shared__ int ws[4];
    int tid = threadIdx.x;
    int idx = blockIdx.x * 256 + tid;
    int4 v = (idx < NN / 4) ? cnt4[idx] : make_int4(0, 0, 0, 0);
    int s = v.x + v.y + v.z + v.w;
#pragma unroll
    for (int o = 32; o; o >>= 1) s += __shfl_xor(s, o, 64);
    if ((tid & 63) == 0) ws[tid >> 6] = s;
    __syncthreads();
    if (tid == 0) bsum[blockIdx.x] = ws[0] + ws[1] + ws[2] + ws[3];
}

// --- phase C: per-block exclusive scan + base from bsum -> off -------------
__global__ __launch_bounds__(256) void scanC_kernel(const int4* __restrict__ cnt4,
                                                    const int* __restrict__ bsum,
                                                    int* __restrict__ off) {
    __shared__ int wsum[4];
    int tid = threadIdx.x, lane = tid & 63, wv = tid >> 6;
    int b = blockIdx.x;
    int bb = (lane < b) ? bsum[lane] : 0;   // b <= 48 < 64
#pragma unroll
    for (int o = 32; o; o >>= 1) bb += __shfl_xor(bb, o, 64);
    int idx = b * 256 + tid;
    int4 v = (idx < NN / 4) ? cnt4[idx] : make_int4(0, 0, 0, 0);
    int tot = v.x + v.y + v.z + v.w;
    int incl = tot;
#pragma unroll
    for (int d = 1; d < 64; d <<= 1) { int t = __shfl_up(incl, d, 64); if (lane >= d) incl += t; }
    if (lane == 63) wsum[wv] = incl;
    __syncthreads();
    int wbase = 0;
#pragma unroll
    for (int j = 0; j < 4; ++j) wbase += (j < wv) ? wsum[j] : 0;
    int excl = bb + wbase + incl - tot;
    if (idx < NN / 4) {
        off[4 * idx]     = excl;
        off[4 * idx + 1] = excl + v.x;
        off[4 * idx + 2] = excl + v.x + v.y;
        off[4 * idx + 3] = excl + v.x + v.y + v.z;
    }
    if (b == 0 && tid == 0) off[NN] = NE;
}

// --- binA: block-local LDS histogram + clustered append into staging -------
template <typename T>
__device__ __forceinline__ void binA_impl(int* lcnt, int* lbase,
                                          const int* __restrict__ src,
                                          const int* __restrict__ tgt,
                                          const T* __restrict__ ea,
                                          const int* __restrict__ off,
                                          int* __restrict__ ccur,
                                          float4* __restrict__ stg) {
    int tid = threadIdx.x;
    for (int i = tid; i < NBUCK; i += 256) lcnt[i] = 0;
    __syncthreads();
    int e0 = blockIdx.x * 2048;
    float ex[8], ey[8], ez[8];
    unsigned ew[8];
    int eb[8], er[8];
#pragma unroll
    for (int k = 0; k < 8; ++k) {
        int e = e0 + (k << 8) + tid;
        if (e < NE) {
            int t = tgt[e];
            int s = src[e];
            eb[k] = t >> 8;
            ew[k] = ((unsigned)t << 16) | (unsigned)s;
            ex[k] = to_f(ea[e * 3 + 0]);
            ey[k] = to_f(ea[e * 3 + 1]);
            ez[k] = to_f(ea[e * 3 + 2]);
            er[k] = atomicAdd(&lcnt[eb[k]], 1);
        } else eb[k] = -1;
    }
    __syncthreads();
    for (int i = tid; i < NBUCK; i += 256) {
        int c = lcnt[i];
        int g = c ? atomicAdd(&ccur[i], c) : 0;
        lbase[i] = off[i << 8] + g;
    }
    __syncthreads();
#pragma unroll
    for (int k = 0; k < 8; ++k) {
        if (eb[k] >= 0) {
            float4 r;
            r.x = ex[k]; r.y = ey[k]; r.z = ez[k];
            r.w = __uint_as_float(ew[k]);
            stg[lbase[eb[k]] + er[k]] = r;
        }
    }
}

__global__ __launch_bounds__(256) void binA_kernel(const int* __restrict__ src,
                                                   const int* __restrict__ tgt,
                                                   const void* ea,
                                                   const int* __restrict__ off,
                                                   const int* __restrict__ flagp,
                                                   int* __restrict__ ccur,
                                                   float4* __restrict__ stg) {
    __shared__ int lcnt[NBUCK];
    __shared__ int lbase[NBUCK];
    if (*flagp) binA_impl<float>(lcnt, lbase, src, tgt, (const float*)ea, off, ccur, stg);
    else        binA_impl<bf16>(lcnt, lbase, src, tgt, (const bf16*)ea, off, ccur, stg);
}

// --- binB: one block per bucket; contiguous read, LDS-ranked local scatter -
__global__ __launch_bounds__(256) void binB_kernel(const float4* __restrict__ stg,
                                                   const int* __restrict__ off,
                                                   float4* __restrict__ edge) {
    __shared__ int lfill[256];
    __shared__ int loff[257];
    int tid = threadIdx.x;
    int n0 = blockIdx.x << 8;
    int nn = min(256, NN - n0);
    for (int i = tid; i < nn; i += 256) lfill[i] = 0;
    for (int i = tid; i <= nn; i += 256) loff[i] = off[n0 + i];
    __syncthreads();
    int cb = loff[0], ce = loff[nn];
    for (int i = cb + tid; i < ce; i += 256) {
        float4 r = stg[i];
        unsigned w = __float_as_uint(r.w);
        int l = (int)(w >> 16) & 255;           // t - n0
        int rk = atomicAdd(&lfill[l], 1);       // LDS atomic
        r.w = __uint_as_float(w & 0xFFFFu);     // final record keeps src only
        edge[loff[l] + rk] = r;
    }
}

// --- linear_pre: 64 rows/block, 4x4 register tile; H stored bf16 -----------
template <typename T>
__device__ __forceinline__ void pre_impl(float (*Xl)[132], const T* __restrict__ x,
                                         const T* __restrict__ w, const T* __restrict__ b,
                                         unsigned short* __restrict__ h) {
    int tid = threadIdx.x;
    int nb  = blockIdx.x * 64;
    if constexpr (sizeof(T) == 2) {
        const ushort4* xg = (const ushort4*)(x + (size_t)nb * IND);
        for (int j = tid; j < 64 * 32; j += 256) {
            int row = j >> 5, kk = (j & 31) * 4;
            ushort4 u = (nb + row < NN) ? xg[j] : make_ushort4(0, 0, 0, 0);
            Xl[row][kk]     = b2f(u.x);
            Xl[row][kk + 1] = b2f(u.y);
            Xl[row][kk + 2] = b2f(u.z);
            Xl[row][kk + 3] = b2f(u.w);
        }
    } else {
        const float4* xg = (const float4*)(x + (size_t)nb * IND);
        for (int j = tid; j < 64 * 32; j += 256) {
            int row = j >> 5, kk = (j & 31) * 4;
            float4 v = (nb + row < NN) ? xg[j] : make_float4(0.f, 0.f, 0.f, 0.f);
            Xl[row][kk] = v.x; Xl[row][kk + 1] = v.y; Xl[row][kk + 2] = v.z; Xl[row][kk + 3] = v.w;
        }
    }
    __syncthreads();
    int tx = tid & 15, ty = tid >> 4, c0 = tx * 4;
    float acc[4][4];
#pragma unroll
    for (int r = 0; r < 4; ++r)
#pragma unroll
        for (int j = 0; j < 4; ++j) acc[r][j] = to_f(b[c0 + j]);
    for (int k = 0; k < IND; k += 4) {
#pragma unroll
        for (int kk = 0; kk < 4; ++kk) {
            float wv[4];
#pragma unroll
            for (int j = 0; j < 4; ++j) wv[j] = to_f(w[(k + kk) * C + c0 + j]);
#pragma unroll
            for (int r = 0; r < 4; ++r) {
                float sv = Xl[ty + 16 * r][k + kk];
#pragma unroll
                for (int j = 0; j < 4; ++j) acc[r][j] += sv * wv[j];
            }
        }
    }
#pragma unroll
    for (int r = 0; r < 4; ++r) {
        int row = nb + ty + 16 * r;
        if (row < NN) {
            ushort4 uv = make_ushort4(f2b(acc[r][0]), f2b(acc[r][1]), f2b(acc[r][2]), f2b(acc[r][3]));
            *(ushort4*)(h + (size_t)row * C + c0) = uv;
        }
    }
}

__global__ __launch_bounds__(256) void pre_kernel(const void* x, const void* w, const void* b,
                                                  const int* __restrict__ flagp,
                                                  unsigned short* __restrict__ h) {
    __shared__ float Xl[64][132];
    if (*flagp) pre_impl<float>(Xl, (const float*)x, (const float*)w, (const float*)b, h);
    else        pre_impl<bf16>(Xl, (const bf16*)x, (const bf16*)w, (const bf16*)b, h);
}

// --- aggregation: one wave/node, 2-stage pipeline (h prefetched 1 iter ahead)
__global__ __launch_bounds__(256) void agg_kernel(const unsigned short* __restrict__ hb,
                                                  const float4* __restrict__ edge,
                                                  const int* __restrict__ off,
                                                  float* __restrict__ s) {
    int f = threadIdx.x & 63;
    int n = blockIdx.x * 4 + (threadIdx.x >> 6);
    int beg = __builtin_amdgcn_readfirstlane(off[n]);
    int end = __builtin_amdgcn_readfirstlane(off[n + 1]);
    float a0 = 0.f, a1 = 0.f, a2 = 0.f;
    int cnt = end - beg;
    int m4 = beg + (cnt & ~3);
    int e = beg;
    if (beg + 8 <= m4) {
        float4 c0 = edge[e],     c1 = edge[e + 1], c2 = edge[e + 2], c3 = edge[e + 3];
        float4 d0 = edge[e + 4], d1 = edge[e + 5], d2 = edge[e + 6], d3 = edge[e + 7];
        float h0 = b2f(hb[(__float_as_int(c0.w) << 6) + f]);
        float h1 = b2f(hb[(__float_as_int(c1.w) << 6) + f]);
        float h2 = b2f(hb[(__float_as_int(c2.w) << 6) + f]);
        float h3 = b2f(hb[(__float_as_int(c3.w) << 6) + f]);
        int e2 = beg + 8;
        while (e2 < m4) {
            float g0 = b2f(hb[(__float_as_int(d0.w) << 6) + f]);
            float g1 = b2f(hb[(__float_as_int(d1.w) << 6) + f]);
            float g2 = b2f(hb[(__float_as_int(d2.w) << 6) + f]);
            float g3 = b2f(hb[(__float_as_int(d3.w) << 6) + f]);
            float4 n0 = edge[e2], n1 = edge[e2 + 1], n2 = edge[e2 + 2], n3 = edge[e2 + 3];
            a0 += c0.x * h0; a1 += c0.y * h0; a2 += c0.z * h0;
            a0 += c1.x * h1; a1 += c1.y * h1; a2 += c1.z * h1;
            a0 += c2.x * h2; a1 += c2.y * h2; a2 += c2.z * h2;
            a0 += c3.x * h3; a1 += c3.y * h3; a2 += c3.z * h3;
            c0 = d0; c1 = d1; c2 = d2; c3 = d3;
            h0 = g0; h1 = g1; h2 = g2; h3 = g3;
            d0 = n0; d1 = n1; d2 = n2; d3 = n3;
            e2 += 4;
        }
        float g0 = b2f(hb[(__float_as_int(d0.w) << 6) + f]);
        float g1 = b2f(hb[(__float_as_int(d1.w) << 6) + f]);
        float g2 = b2f(hb[(__float_as_int(d2.w) << 6) + f]);
        float g3 = b2f(hb[(__float_as_int(d3.w) << 6) + f]);
        a0 += c0.x * h0; a1 += c0.y * h0; a2 += c0.z * h0;
        a0 += c1.x * h1; a1 += c1.y * h1; a2 += c1.z * h1;
        a0 += c2.x * h2; a1 += c2.y * h2; a2 += c2.z * h2;
        a0 += c3.x * h3; a1 += c3.y * h3; a2 += c3.z * h3;
        a0 += d0.x * g0; a1 += d0.y * g0; a2 += d0.z * g0;
        a0 += d1.x * g1; a1 += d1.y * g1; a2 += d1.z * g1;
        a0 += d2.x * g2; a1 += d2.y * g2; a2 += d2.z * g2;
        a0 += d3.x * g3; a1 += d3.y * g3; a2 += d3.z * g3;
        e = m4;
    } else if (beg + 4 <= m4) {
        float4 c0 = edge[e], c1 = edge[e + 1], c2 = edge[e + 2], c3 = edge[e + 3];
        float h0 = b2f(hb[(__float_as_int(c0.w) << 6) + f]);
        float h1 = b2f(hb[(__float_as_int(c1.w) << 6) + f]);
        float h2 = b2f(hb[(__float_as_int(c2.w) << 6) + f]);
        float h3 = b2f(hb[(__float_as_int(c3.w) << 6) + f]);
        a0 += c0.x * h0; a1 += c0.y * h0; a2 += c0.z * h0;
        a0 += c1.x * h1; a1 += c1.y * h1; a2 += c1.z * h1;
        a0 += c2.x * h2; a1 += c2.y * h2; a2 += c2.z * h2;
        a0 += c3.x * h3; a1 += c3.y * h3; a2 += c3.z * h3;
        e = m4;
    }
    for (; e < end; ++e) {
        float4 r = edge[e];
        float hv = b2f(hb[(__float_as_int(r.w) << 6) + f]);
        a0 += r.x * hv; a1 += r.y * hv; a2 += r.z * hv;
    }
    float iv = 1.0f / fmaxf((float)cnt, 1.0f);
    float* so = s + n * 192;
    so[f] = a0 * iv; so[64 + f] = a1 * iv; so[128 + f] = a2 * iv;
}

// --- dense via MFMA: out = S @ W + b; hi/lo bf16 split keeps fp32 precision
// 4 waves/block; wave tile 16 rows x 64 cols; K=192 in 6 steps of 32.
// W staged in LDS in fragment order: idx = ((ct*6+t)*64 + lane)*8 + j,
//   k = 32*t + (lane>>4)*8 + j, col = 16*ct + (lane&15)  (A uses same k map)
// C/D mapping (m89-verified): col = lane&15, row = (lane>>4)*4 + reg.
// MODE 0: relu -> hout (bf16); MODE 1: L2-normalize -> out (T)
template <typename T, int MODE>
__device__ __forceinline__ void gemmM_impl(unsigned short* Wh, unsigned short* Wlo,
                                           const float* __restrict__ s,
                                           const T* __restrict__ w, const T* __restrict__ b,
                                           unsigned short* __restrict__ hout, T* __restrict__ out) {
    int tid = threadIdx.x;
    int nb  = blockIdx.x * 64;
    // stage W fragments (hi/lo split in fp32 mode; exact bf16 otherwise)
    for (int idx = tid; idx < 12288; idx += 256) {
        int j    = idx & 7;
        int lane = (idx >> 3) & 63;
        int r2   = idx >> 9;           // 0..23
        int tt   = r2 % 6;
        int ct   = r2 / 6;
        int k    = 32 * tt + ((lane >> 4) << 3) + j;
        int col  = 16 * ct + (lane & 15);
        if constexpr (sizeof(T) == 4) {
            float v = ((const float*)w)[k * 64 + col];
            unsigned short hi = f2b(v);
            Wh[idx]  = hi;
            Wlo[idx] = f2b(v - b2f(hi));
        } else {
            Wh[idx] = ((const unsigned short*)w)[k * 64 + col];
        }
    }
    __syncthreads();
    int lane = tid & 63, wv = tid >> 6;
    int m = lane & 15, g = lane >> 4;
    int arow = nb + wv * 16 + m;                 // A-load row for this lane
    bool okrow = arow < NN;
    const float* srow = s + (size_t)arow * 192 + g * 8;
    f4v acc[4] = {};
    for (int t = 0; t < 6; ++t) {
        float av[8];
        if (okrow) {
            float4 v0 = *(const float4*)(srow + t * 32);
            float4 v1 = *(const float4*)(srow + t * 32 + 4);
            av[0] = v0.x; av[1] = v0.y; av[2] = v0.z; av[3] = v0.w;
            av[4] = v1.x; av[5] = v1.y; av[6] = v1.z; av[7] = v1.w;
        } else {
#pragma unroll
            for (int j = 0; j < 8; ++j) av[j] = 0.f;
        }
        s8v ahi, alo;
#pragma unroll
        for (int j = 0; j < 8; ++j) {
            unsigned short hi = f2b(av[j]);
            ahi[j] = (short)hi;
            alo[j] = (short)f2b(av[j] - b2f(hi));
        }
#pragma unroll
        for (int ct = 0; ct < 4; ++ct) {
            int fo = ((ct * 6 + t) * 64 + lane) * 8;
            s8v bh = *(const s8v*)&Wh[fo];
            acc[ct] = __builtin_amdgcn_mfma_f32_16x16x32_bf16(ahi, bh, acc[ct], 0, 0, 0);
            acc[ct] = __builtin_amdgcn_mfma_f32_16x16x32_bf16(alo, bh, acc[ct], 0, 0, 0);
            if constexpr (sizeof(T) == 4) {
                s8v bl = *(const s8v*)&Wlo[fo];
                acc[ct] = __builtin_amdgcn_mfma_f32_16x16x32_bf16(ahi, bl, acc[ct], 0, 0, 0);
            }
        }
    }
    // epilogue: lane holds D rows (g*4+r), col 16*ct+m
    float vv[4][4];
#pragma unroll
    for (int ct = 0; ct < 4; ++ct) {
        float bv = to_f(b[16 * ct + m]);
#pragma unroll
        for (int r = 0; r < 4; ++r) vv[ct][r] = acc[ct][r] + bv;
    }
    if constexpr (MODE == 0) {
#pragma unroll
        for (int r = 0; r < 4; ++r) {
            int drow = nb + wv * 16 + g * 4 + r;
            if (drow < NN) {
#pragma unroll
                for (int ct = 0; ct < 4; ++ct)
                    hout[(size_t)drow * C + 16 * ct + m] = f2b(fmaxf(vv[ct][r], 0.f));
            }
        }
    } else {
#pragma unroll
        for (int r = 0; r < 4; ++r) {
            float sq = vv[0][r] * vv[0][r] + vv[1][r] * vv[1][r]
                     + vv[2][r] * vv[2][r] + vv[3][r] * vv[3][r];
#pragma unroll
            for (int o = 1; o < 16; o <<= 1) sq += __shfl_xor(sq, o, 64);
            float innorm = 1.0f / fmaxf(sqrtf(sq), 1e-12f);
            int drow = nb + wv * 16 + g * 4 + r;
            if (drow < NN) {
#pragma unroll
                for (int ct = 0; ct < 4; ++ct) {
                    float rv = vv[ct][r] * innorm;
                    if constexpr (sizeof(T) == 2) out[(size_t)drow * C + 16 * ct + m] = __float2bfloat16(rv);
                    else                          out[(size_t)drow * C + 16 * ct + m] = rv;
                }
            }
        }
    }
}

__global__ __launch_bounds__(256) void gemm_relu(const float* __restrict__ s, const void* w,
                                                 const void* b, const int* __restrict__ flagp,
                                                 unsigned short* __restrict__ hout) {
    __shared__ unsigned short Wh[12288];
    __shared__ unsigned short Wlo[12288];
    if (*flagp) gemmM_impl<float, 0>(Wh, Wlo, s, (const float*)w, (const float*)b, hout, (float*)nullptr);
    else        gemmM_impl<bf16, 0>(Wh, Wlo, s, (const bf16*)w, (const bf16*)b, hout, (bf16*)nullptr);
}

__global__ __launch_bounds__(256) void gemm_norm(const float* __restrict__ s, const void* w,
                                                 const void* b, const int* __restrict__ flagp,
                                                 void* out) {
    __shared__ unsigned short Wh[12288];
    __shared__ unsigned short Wlo[12288];
    if (*flagp) gemmM_impl<float, 1>(Wh, Wlo, s, (const float*)w, (const float*)b, nullptr, (float*)out);
    else        gemmM_impl<bf16, 1>(Wh, Wlo, s, (const bf16*)w, (const bf16*)b, nullptr, (bf16*)out);
}

extern "C" void kernel_launch(void* const* d_in, const int* in_sizes, int n_in,
                              void* d_out, int out_size, void* d_ws, size_t ws_size,
                              hipStream_t stream) {
    const void* x     = d_in[0];
    const int*  ei    = (const int*)d_in[1];
    const void* ea    = d_in[2];
    const void* pre_w = d_in[3];
    const void* pre_b = d_in[4];
    const void* W[3]  = {d_in[5], d_in[7], d_in[9]};
    const void* B[3]  = {d_in[6], d_in[8], d_in[10]};
    const int* src = ei;
    const int* tgt = ei + NE;

    // ws layout: EDGE f4[NE] | S f32[NN*192] (staging STG overlays S)
    //            | H bf16[NN*64] | CNT[NN] | CCUR[256] | OFF[NN+8] | BSUM[64] | FLAG
    float4*         EDGE = (float4*)d_ws;                            // 12.8 MB
    float*          S    = (float*)(EDGE + NE);                      // 38.4 MB
    float4*         STG  = (float4*)S;                               // overlay (12.8 MB)
    unsigned short* H    = (unsigned short*)(S + (size_t)NN * 192);  // 6.4 MB
    int*            CNT  = (int*)(H + (size_t)NN * C);               // 16B-aligned
    int*            CCUR = CNT + NN;
    int*            OFF  = CCUR + 256;
    int*            BSUM = OFF + NN + 8;
    int*            FLAG = BSUM + 64;

    detect_kernel<<<1, 64, 0, stream>>>((const unsigned*)x, FLAG);
    hipMemsetAsync(CNT, 0, (NN + 256) * sizeof(int), stream);   // CNT + CCUR
    count_kernel<<<(NE + 255) / 256, 256, 0, stream>>>(tgt, CNT);
    scanA_kernel<<<(NN / 4 + 255) / 256, 256, 0, stream>>>((const int4*)CNT, BSUM);
    scanC_kernel<<<(NN / 4 + 255) / 256, 256, 0, stream>>>((const int4*)CNT, BSUM, OFF);
    binA_kernel<<<(NE + 2047) / 2048, 256, 0, stream>>>(src, tgt, ea, OFF, FLAG, CCUR, STG);
    binB_kernel<<<NBUCK, 256, 0, stream>>>(STG, OFF, EDGE);
    pre_kernel<<<(NN + 63) / 64, 256, 0, stream>>>(x, pre_w, pre_b, FLAG, H);

    int nblk = (NN + 63) / 64;
    for (int l = 0; l < 3; ++l) {
        agg_kernel<<<NN / 4, 256, 0, stream>>>(H, EDGE, OFF, S);
        if (l < 2)
            gemm_relu<<<nblk, 256, 0, stream>>>(S, W[l], B[l], FLAG, H);
        else
            gemm_norm<<<nblk, 256, 0, stream>>>(S, W[l], B[l], FLAG, d_out);
    }
}

// Round 11
// 317.942 us; speedup vs baseline: 1.3142x; 1.1253x over previous
//
#include <hip/hip_runtime.h>
#include <hip/hip_bf16.h>

#define NN 50000
#define NE 800000
#define IND 128
#define C 64       // FEAT = HID = OUT
#define NBUCK 196  // coarse buckets of 256 nodes: 196*256 = 50176 >= NN

typedef __hip_bfloat16 bf16;
typedef __attribute__((ext_vector_type(8))) short s8v;    // 8 bf16 (4 VGPRs)
typedef __attribute__((ext_vector_type(4))) float f4v;    // MFMA C/D

__device__ __forceinline__ float to_f(float v) { return v; }
__device__ __forceinline__ float to_f(bf16 v)  { return __bfloat162float(v); }

// bf16 <-> fp32 raw helpers (H is stored as ushort bf16 internally)
__device__ __forceinline__ unsigned short f2b(float v) {
    unsigned u = __float_as_uint(v);
    return (unsigned short)((u + 0x7FFFu + ((u >> 16) & 1u)) >> 16);   // RNE
}
__device__ __forceinline__ float b2f(unsigned short u) {
    return __uint_as_float((unsigned)u << 16);
}

// --- dtype detect: float inputs fp32 (flag=1) or bf16 (flag=0)? ------------
__global__ void detect_kernel(const unsigned* __restrict__ xu, int* __restrict__ flag) {
    int lane = threadIdx.x;
    unsigned u  = xu[lane];
    unsigned ex = (u >> 7) & 0xFF;
    int vote = (ex >= 90 && ex <= 144) ? 1 : 0;
#pragma unroll
    for (int off = 32; off; off >>= 1) vote += __shfl_xor(vote, off, 64);
    if (lane == 0) *flag = (vote < 40) ? 1 : 0;
}

// --- degree histogram ------------------------------------------------------
__global__ void count_kernel(const int* __restrict__ tgt, int* __restrict__ cnt) {
    int e = blockIdx.x * blockDim.x + threadIdx.x;
    if (e < NE) atomicAdd(&cnt[tgt[e]], 1);
}

// --- multi-block scan: phase A = per-block (1024 counts) totals ------------
__global__ __launch_bounds__(256) void scanA_kernel(const int4* __restrict__ cnt4,
                                                    int* __restrict__ bsum) {
    __shared__ int ws[4];
    int tid = threadIdx.x;
    int idx = blockIdx.x * 256 + tid;
    int4 v = (idx < NN / 4) ? cnt4[idx] : make_int4(0, 0, 0, 0);
    int s = v.x + v.y + v.z + v.w;
#pragma unroll
    for (int o = 32; o; o >>= 1) s += __shfl_xor(s, o, 64);
    if ((tid & 63) == 0) ws[tid >> 6] = s;
    __syncthreads();
    if (tid == 0) bsum[blockIdx.x] = ws[0] + ws[1] + ws[2] + ws[3];
}

// --- phase C: per-block exclusive scan + base from bsum -> off -------------
__global__ __launch_bounds__(256) void scanC_kernel(const int4* __restrict__ cnt4,
                                                    const int* __restrict__ bsum,
                                                    int* __restrict__ off) {
    __shared__ int wsum[4];
    int tid = threadIdx.x, lane = tid & 63, wv = tid >> 6;
    int b = blockIdx.x;
    int bb = (lane < b) ? bsum[lane] : 0;   // b <= 48 < 64
#pragma unroll
    for (int o = 32; o; o >>= 1) bb += __shfl_xor(bb, o, 64);
    int idx = b * 256 + tid;
    int4 v = (idx < NN / 4) ? cnt4[idx] : make_int4(0, 0, 0, 0);
    int tot = v.x + v.y + v.z + v.w;
    int incl = tot;
#pragma unroll
    for (int d = 1; d < 64; d <<= 1) { int t = __shfl_up(incl, d, 64); if (lane >= d) incl += t; }
    if (lane == 63) wsum[wv] = incl;
    __syncthreads();
    int wbase = 0;
#pragma unroll
    for (int j = 0; j < 4; ++j) wbase += (j < wv) ? wsum[j] : 0;
    int excl = bb + wbase + incl - tot;
    if (idx < NN / 4) {
        off[4 * idx]     = excl;
        off[4 * idx + 1] = excl + v.x;
        off[4 * idx + 2] = excl + v.x + v.y;
        off[4 * idx + 3] = excl + v.x + v.y + v.z;
    }
    if (b == 0 && tid == 0) off[NN] = NE;
}

// --- binA: block-local LDS histogram + clustered append into staging -------
template <typename T>
__device__ __forceinline__ void binA_impl(int* lcnt, int* lbase,
                                          const int* __restrict__ src,
                                          const int* __restrict__ tgt,
                                          const T* __restrict__ ea,
                                          const int* __restrict__ off,
                                          int* __restrict__ ccur,
                                          float4* __restrict__ stg) {
    int tid = threadIdx.x;
    for (int i = tid; i < NBUCK; i += 256) lcnt[i] = 0;
    __syncthreads();
    int e0 = blockIdx.x * 2048;
    float ex[8], ey[8], ez[8];
    unsigned ew[8];
    int eb[8], er[8];
#pragma unroll
    for (int k = 0; k < 8; ++k) {
        int e = e0 + (k << 8) + tid;
        if (e < NE) {
            int t = tgt[e];
            int s = src[e];
            eb[k] = t >> 8;
            ew[k] = ((unsigned)t << 16) | (unsigned)s;
            ex[k] = to_f(ea[e * 3 + 0]);
            ey[k] = to_f(ea[e * 3 + 1]);
            ez[k] = to_f(ea[e * 3 + 2]);
            er[k] = atomicAdd(&lcnt[eb[k]], 1);
        } else eb[k] = -1;
    }
    __syncthreads();
    for (int i = tid; i < NBUCK; i += 256) {
        int c = lcnt[i];
        int g = c ? atomicAdd(&ccur[i], c) : 0;
        lbase[i] = off[i << 8] + g;
    }
    __syncthreads();
#pragma unroll
    for (int k = 0; k < 8; ++k) {
        if (eb[k] >= 0) {
            float4 r;
            r.x = ex[k]; r.y = ey[k]; r.z = ez[k];
            r.w = __uint_as_float(ew[k]);
            stg[lbase[eb[k]] + er[k]] = r;
        }
    }
}

__global__ __launch_bounds__(256) void binA_kernel(const int* __restrict__ src,
                                                   const int* __restrict__ tgt,
                                                   const void* ea,
                                                   const int* __restrict__ off,
                                                   const int* __restrict__ flagp,
                                                   int* __restrict__ ccur,
                                                   float4* __restrict__ stg) {
    __shared__ int lcnt[NBUCK];
    __shared__ int lbase[NBUCK];
    if (*flagp) binA_impl<float>(lcnt, lbase, src, tgt, (const float*)ea, off, ccur, stg);
    else        binA_impl<bf16>(lcnt, lbase, src, tgt, (const bf16*)ea, off, ccur, stg);
}

// --- binB: one block per bucket; contiguous read, LDS-ranked local scatter -
__global__ __launch_bounds__(256) void binB_kernel(const float4* __restrict__ stg,
                                                   const int* __restrict__ off,
                                                   float4* __restrict__ edge) {
    __shared__ int lfill[256];
    __shared__ int loff[257];
    int tid = threadIdx.x;
    int n0 = blockIdx.x << 8;
    int nn = min(256, NN - n0);
    for (int i = tid; i < nn; i += 256) lfill[i] = 0;
    for (int i = tid; i <= nn; i += 256) loff[i] = off[n0 + i];
    __syncthreads();
    int cb = loff[0], ce = loff[nn];
    for (int i = cb + tid; i < ce; i += 256) {
        float4 r = stg[i];
        unsigned w = __float_as_uint(r.w);
        int l = (int)(w >> 16) & 255;           // t - n0
        int rk = atomicAdd(&lfill[l], 1);       // LDS atomic
        r.w = __uint_as_float(w & 0xFFFFu);     // final record keeps src only
        edge[loff[l] + rk] = r;
    }
}

// --- wprep: convert weight [K][64] into MFMA fragment order (once/layer) ---
// idx = ((ct*nT + t)*64 + lane)*8 + j ; k = 32t + (lane>>4)*8 + j ;
// col = 16ct + (lane&15). fp32 mode: hi/lo bf16 split. (maps verified r10)
template <typename T>
__device__ __forceinline__ void wprep_impl(const T* __restrict__ w, int nT,
                                           unsigned short* __restrict__ oh,
                                           unsigned short* __restrict__ ol) {
    int idx = blockIdx.x * 256 + threadIdx.x;
    if (idx >= 2048 * nT) return;
    int j    = idx & 7;
    int lane = (idx >> 3) & 63;
    int r2   = idx >> 9;
    int t    = r2 % nT;
    int ct   = r2 / nT;
    int k    = 32 * t + ((lane >> 4) << 3) + j;
    int col  = 16 * ct + (lane & 15);
    if constexpr (sizeof(T) == 4) {
        float v = ((const float*)w)[k * 64 + col];
        unsigned short hi = f2b(v);
        oh[idx] = hi;
        ol[idx] = f2b(v - b2f(hi));
    } else {
        oh[idx] = ((const unsigned short*)w)[k * 64 + col];
    }
}

__global__ void wprep_kernel(const void* w, const int* __restrict__ flagp, int nT,
                             unsigned short* __restrict__ oh, unsigned short* __restrict__ ol) {
    if (*flagp) wprep_impl<float>((const float*)w, nT, oh, ol);
    else        wprep_impl<bf16>((const bf16*)w, nT, oh, ol);
}

// --- linear_pre via MFMA: h = x @ pre_w + pre_b (K=128, 4 t-steps) ---------
template <typename T>
__device__ __forceinline__ void preM_impl(const T* __restrict__ x,
                                          const unsigned short* __restrict__ wfh,
                                          const unsigned short* __restrict__ wfl,
                                          const T* __restrict__ b,
                                          unsigned short* __restrict__ h) {
    int tid = threadIdx.x;
    int nb  = blockIdx.x * 64;
    int lane = tid & 63, wv = tid >> 6;
    int m = lane & 15, g = lane >> 4;
    int arow = nb + wv * 16 + m;
    bool okrow = arow < NN;
    f4v acc[4] = {};
    for (int t = 0; t < 4; ++t) {
        if constexpr (sizeof(T) == 4) {
            float av[8];
            if (okrow) {
                const float* xr = (const float*)x + (size_t)arow * IND + t * 32 + g * 8;
                float4 v0 = *(const float4*)xr;
                float4 v1 = *(const float4*)(xr + 4);
                av[0] = v0.x; av[1] = v0.y; av[2] = v0.z; av[3] = v0.w;
                av[4] = v1.x; av[5] = v1.y; av[6] = v1.z; av[7] = v1.w;
            } else {
#pragma unroll
                for (int j = 0; j < 8; ++j) av[j] = 0.f;
            }
            s8v ahi, alo;
#pragma unroll
            for (int j = 0; j < 8; ++j) {
                unsigned short hi = f2b(av[j]);
                ahi[j] = (short)hi;
                alo[j] = (short)f2b(av[j] - b2f(hi));
            }
#pragma unroll
            for (int ct = 0; ct < 4; ++ct) {
                int fo = ((ct * 4 + t) * 64 + lane) * 8;
                s8v bh = *(const s8v*)&wfh[fo];
                s8v bl = *(const s8v*)&wfl[fo];
                acc[ct] = __builtin_amdgcn_mfma_f32_16x16x32_bf16(ahi, bh, acc[ct], 0, 0, 0);
                acc[ct] = __builtin_amdgcn_mfma_f32_16x16x32_bf16(alo, bh, acc[ct], 0, 0, 0);
                acc[ct] = __builtin_amdgcn_mfma_f32_16x16x32_bf16(ahi, bl, acc[ct], 0, 0, 0);
            }
        } else {
            s8v ahi = {};
            if (okrow)
                ahi = *(const s8v*)((const unsigned short*)x + (size_t)arow * IND + t * 32 + g * 8);
#pragma unroll
            for (int ct = 0; ct < 4; ++ct) {
                int fo = ((ct * 4 + t) * 64 + lane) * 8;
                s8v bh = *(const s8v*)&wfh[fo];
                acc[ct] = __builtin_amdgcn_mfma_f32_16x16x32_bf16(ahi, bh, acc[ct], 0, 0, 0);
            }
        }
    }
    // epilogue: lane holds D rows (g*4+r), col 16*ct+m ; no activation
#pragma unroll
    for (int r = 0; r < 4; ++r) {
        int drow = nb + wv * 16 + g * 4 + r;
        if (drow < NN) {
#pragma unroll
            for (int ct = 0; ct < 4; ++ct)
                h[(size_t)drow * C + 16 * ct + m] = f2b(acc[ct][r] + to_f(b[16 * ct + m]));
        }
    }
}

__global__ __launch_bounds__(256) void preM_kernel(const void* x,
                                                   const unsigned short* __restrict__ wfh,
                                                   const unsigned short* __restrict__ wfl,
                                                   const void* b, const int* __restrict__ flagp,
                                                   unsigned short* __restrict__ h) {
    if (*flagp) preM_impl<float>((const float*)x, wfh, wfl, (const float*)b, h);
    else        preM_impl<bf16>((const bf16*)x, wfh, wfl, (const bf16*)b, h);
}

// --- aggregation: one wave/node, 2-stage pipeline (h prefetched 1 iter ahead)
__global__ __launch_bounds__(256) void agg_kernel(const unsigned short* __restrict__ hb,
                                                  const float4* __restrict__ edge,
                                                  const int* __restrict__ off,
                                                  float* __restrict__ s) {
    int f = threadIdx.x & 63;
    int n = blockIdx.x * 4 + (threadIdx.x >> 6);
    int beg = __builtin_amdgcn_readfirstlane(off[n]);
    int end = __builtin_amdgcn_readfirstlane(off[n + 1]);
    float a0 = 0.f, a1 = 0.f, a2 = 0.f;
    int cnt = end - beg;
    int m4 = beg + (cnt & ~3);
    int e = beg;
    if (beg + 8 <= m4) {
        float4 c0 = edge[e],     c1 = edge[e + 1], c2 = edge[e + 2], c3 = edge[e + 3];
        float4 d0 = edge[e + 4], d1 = edge[e + 5], d2 = edge[e + 6], d3 = edge[e + 7];
        float h0 = b2f(hb[(__float_as_int(c0.w) << 6) + f]);
        float h1 = b2f(hb[(__float_as_int(c1.w) << 6) + f]);
        float h2 = b2f(hb[(__float_as_int(c2.w) << 6) + f]);
        float h3 = b2f(hb[(__float_as_int(c3.w) << 6) + f]);
        int e2 = beg + 8;
        while (e2 < m4) {
            float g0 = b2f(hb[(__float_as_int(d0.w) << 6) + f]);
            float g1 = b2f(hb[(__float_as_int(d1.w) << 6) + f]);
            float g2 = b2f(hb[(__float_as_int(d2.w) << 6) + f]);
            float g3 = b2f(hb[(__float_as_int(d3.w) << 6) + f]);
            float4 n0 = edge[e2], n1 = edge[e2 + 1], n2 = edge[e2 + 2], n3 = edge[e2 + 3];
            a0 += c0.x * h0; a1 += c0.y * h0; a2 += c0.z * h0;
            a0 += c1.x * h1; a1 += c1.y * h1; a2 += c1.z * h1;
            a0 += c2.x * h2; a1 += c2.y * h2; a2 += c2.z * h2;
            a0 += c3.x * h3; a1 += c3.y * h3; a2 += c3.z * h3;
            c0 = d0; c1 = d1; c2 = d2; c3 = d3;
            h0 = g0; h1 = g1; h2 = g2; h3 = g3;
            d0 = n0; d1 = n1; d2 = n2; d3 = n3;
            e2 += 4;
        }
        float g0 = b2f(hb[(__float_as_int(d0.w) << 6) + f]);
        float g1 = b2f(hb[(__float_as_int(d1.w) << 6) + f]);
        float g2 = b2f(hb[(__float_as_int(d2.w) << 6) + f]);
        float g3 = b2f(hb[(__float_as_int(d3.w) << 6) + f]);
        a0 += c0.x * h0; a1 += c0.y * h0; a2 += c0.z * h0;
        a0 += c1.x * h1; a1 += c1.y * h1; a2 += c1.z * h1;
        a0 += c2.x * h2; a1 += c2.y * h2; a2 += c2.z * h2;
        a0 += c3.x * h3; a1 += c3.y * h3; a2 += c3.z * h3;
        a0 += d0.x * g0; a1 += d0.y * g0; a2 += d0.z * g0;
        a0 += d1.x * g1; a1 += d1.y * g1; a2 += d1.z * g1;
        a0 += d2.x * g2; a1 += d2.y * g2; a2 += d2.z * g2;
        a0 += d3.x * g3; a1 += d3.y * g3; a2 += d3.z * g3;
        e = m4;
    } else if (beg + 4 <= m4) {
        float4 c0 = edge[e], c1 = edge[e + 1], c2 = edge[e + 2], c3 = edge[e + 3];
        float h0 = b2f(hb[(__float_as_int(c0.w) << 6) + f]);
        float h1 = b2f(hb[(__float_as_int(c1.w) << 6) + f]);
        float h2 = b2f(hb[(__float_as_int(c2.w) << 6) + f]);
        float h3 = b2f(hb[(__float_as_int(c3.w) << 6) + f]);
        a0 += c0.x * h0; a1 += c0.y * h0; a2 += c0.z * h0;
        a0 += c1.x * h1; a1 += c1.y * h1; a2 += c1.z * h1;
        a0 += c2.x * h2; a1 += c2.y * h2; a2 += c2.z * h2;
        a0 += c3.x * h3; a1 += c3.y * h3; a2 += c3.z * h3;
        e = m4;
    }
    for (; e < end; ++e) {
        float4 r = edge[e];
        float hv = b2f(hb[(__float_as_int(r.w) << 6) + f]);
        a0 += r.x * hv; a1 += r.y * hv; a2 += r.z * hv;
    }
    float iv = 1.0f / fmaxf((float)cnt, 1.0f);
    float* so = s + n * 192;
    so[f] = a0 * iv; so[64 + f] = a1 * iv; so[128 + f] = a2 * iv;
}

// --- dense via MFMA, fragments direct from prepped global (no LDS) ---------
// C/D mapping (m89-verified): col = lane&15, row = (lane>>4)*4 + reg.
// MODE 0: relu -> hout (bf16); MODE 1: L2-normalize -> out (T)
template <typename T, int MODE>
__device__ __forceinline__ void gemmM_impl(const float* __restrict__ s,
                                           const unsigned short* __restrict__ wfh,
                                           const unsigned short* __restrict__ wfl,
                                           const T* __restrict__ b,
                                           unsigned short* __restrict__ hout, T* __restrict__ out) {
    int tid = threadIdx.x;
    int nb  = blockIdx.x * 64;
    int lane = tid & 63, wv = tid >> 6;
    int m = lane & 15, g = lane >> 4;
    int arow = nb + wv * 16 + m;
    bool okrow = arow < NN;
    const float* srow = s + (size_t)arow * 192 + g * 8;
    f4v acc[4] = {};
    for (int t = 0; t < 6; ++t) {
        float av[8];
        if (okrow) {
            float4 v0 = *(const float4*)(srow + t * 32);
            float4 v1 = *(const float4*)(srow + t * 32 + 4);
            av[0] = v0.x; av[1] = v0.y; av[2] = v0.z; av[3] = v0.w;
            av[4] = v1.x; av[5] = v1.y; av[6] = v1.z; av[7] = v1.w;
        } else {
#pragma unroll
            for (int j = 0; j < 8; ++j) av[j] = 0.f;
        }
        s8v ahi, alo;
#pragma unroll
        for (int j = 0; j < 8; ++j) {
            unsigned short hi = f2b(av[j]);
            ahi[j] = (short)hi;
            alo[j] = (short)f2b(av[j] - b2f(hi));
        }
#pragma unroll
        for (int ct = 0; ct < 4; ++ct) {
            int fo = ((ct * 6 + t) * 64 + lane) * 8;
            s8v bh = *(const s8v*)&wfh[fo];
            acc[ct] = __builtin_amdgcn_mfma_f32_16x16x32_bf16(ahi, bh, acc[ct], 0, 0, 0);
            acc[ct] = __builtin_amdgcn_mfma_f32_16x16x32_bf16(alo, bh, acc[ct], 0, 0, 0);
            if constexpr (sizeof(T) == 4) {
                s8v bl = *(const s8v*)&wfl[fo];
                acc[ct] = __builtin_amdgcn_mfma_f32_16x16x32_bf16(ahi, bl, acc[ct], 0, 0, 0);
            }
        }
    }
    float vv[4][4];
#pragma unroll
    for (int ct = 0; ct < 4; ++ct) {
        float bv = to_f(b[16 * ct + m]);
#pragma unroll
        for (int r = 0; r < 4; ++r) vv[ct][r] = acc[ct][r] + bv;
    }
    if constexpr (MODE == 0) {
#pragma unroll
        for (int r = 0; r < 4; ++r) {
            int drow = nb + wv * 16 + g * 4 + r;
            if (drow < NN) {
#pragma unroll
                for (int ct = 0; ct < 4; ++ct)
                    hout[(size_t)drow * C + 16 * ct + m] = f2b(fmaxf(vv[ct][r], 0.f));
            }
        }
    } else {
#pragma unroll
        for (int r = 0; r < 4; ++r) {
            float sq = vv[0][r] * vv[0][r] + vv[1][r] * vv[1][r]
                     + vv[2][r] * vv[2][r] + vv[3][r] * vv[3][r];
#pragma unroll
            for (int o = 1; o < 16; o <<= 1) sq += __shfl_xor(sq, o, 64);
            float innorm = 1.0f / fmaxf(sqrtf(sq), 1e-12f);
            int drow = nb + wv * 16 + g * 4 + r;
            if (drow < NN) {
#pragma unroll
                for (int ct = 0; ct < 4; ++ct) {
                    float rv = vv[ct][r] * innorm;
                    if constexpr (sizeof(T) == 2) out[(size_t)drow * C + 16 * ct + m] = __float2bfloat16(rv);
                    else                          out[(size_t)drow * C + 16 * ct + m] = rv;
                }
            }
        }
    }
}

__global__ __launch_bounds__(256) void gemm_relu(const float* __restrict__ s,
                                                 const unsigned short* __restrict__ wfh,
                                                 const unsigned short* __restrict__ wfl,
                                                 const void* b, const int* __restrict__ flagp,
                                                 unsigned short* __restrict__ hout) {
    if (*flagp) gemmM_impl<float, 0>(s, wfh, wfl, (const float*)b, hout, (float*)nullptr);
    else        gemmM_impl<bf16, 0>(s, wfh, wfl, (const bf16*)b, hout, (bf16*)nullptr);
}

__global__ __launch_bounds__(256) void gemm_norm(const float* __restrict__ s,
                                                 const unsigned short* __restrict__ wfh,
                                                 const unsigned short* __restrict__ wfl,
                                                 const void* b, const int* __restrict__ flagp,
                                                 void* out) {
    if (*flagp) gemmM_impl<float, 1>(s, wfh, wfl, (const float*)b, nullptr, (float*)out);
    else        gemmM_impl<bf16, 1>(s, wfh, wfl, (const bf16*)b, nullptr, (bf16*)out);
}

extern "C" void kernel_launch(void* const* d_in, const int* in_sizes, int n_in,
                              void* d_out, int out_size, void* d_ws, size_t ws_size,
                              hipStream_t stream) {
    const void* x     = d_in[0];
    const int*  ei    = (const int*)d_in[1];
    const void* ea    = d_in[2];
    const void* pre_w = d_in[3];
    const void* pre_b = d_in[4];
    const void* W[3]  = {d_in[5], d_in[7], d_in[9]};
    const void* B[3]  = {d_in[6], d_in[8], d_in[10]};
    const int* src = ei;
    const int* tgt = ei + NE;

    // ws layout: EDGE f4[NE] | S f32[NN*192] (staging STG overlays S)
    //            | H bf16[NN*64] | CNT[NN] | CCUR[256] | OFF[NN+8] | BSUM[64] | FLAG
    //            | WPH[8192] WPL[8192] | WFH[3*12288] WFL[3*12288]  (fragment-order weights)
    float4*         EDGE = (float4*)d_ws;                            // 12.8 MB
    float*          S    = (float*)(EDGE + NE);                      // 38.4 MB
    float4*         STG  = (float4*)S;                               // overlay (12.8 MB)
    unsigned short* H    = (unsigned short*)(S + (size_t)NN * 192);  // 6.4 MB
    int*            CNT  = (int*)(H + (size_t)NN * C);               // 16B-aligned
    int*            CCUR = CNT + NN;
    int*            OFF  = CCUR + 256;
    int*            BSUM = OFF + NN + 8;
    int*            FLAG = BSUM + 64;
    unsigned short* WPH  = (unsigned short*)(FLAG + 16);
    unsigned short* WPL  = WPH + 8192;
    unsigned short* WFH  = WPL + 8192;            // + l*12288
    unsigned short* WFL  = WFH + 3 * 12288;       // + l*12288

    detect_kernel<<<1, 64, 0, stream>>>((const unsigned*)x, FLAG);
    wprep_kernel<<<32, 256, 0, stream>>>(pre_w, FLAG, 4, WPH, WPL);
    for (int l = 0; l < 3; ++l)
        wprep_kernel<<<48, 256, 0, stream>>>(W[l], FLAG, 6, WFH + l * 12288, WFL + l * 12288);
    hipMemsetAsync(CNT, 0, (NN + 256) * sizeof(int), stream);   // CNT + CCUR
    count_kernel<<<(NE + 255) / 256, 256, 0, stream>>>(tgt, CNT);
    scanA_kernel<<<(NN / 4 + 255) / 256, 256, 0, stream>>>((const int4*)CNT, BSUM);
    scanC_kernel<<<(NN / 4 + 255) / 256, 256, 0, stream>>>((const int4*)CNT, BSUM, OFF);
    binA_kernel<<<(NE + 2047) / 2048, 256, 0, stream>>>(src, tgt, ea, OFF, FLAG, CCUR, STG);
    binB_kernel<<<NBUCK, 256, 0, stream>>>(STG, OFF, EDGE);
    preM_kernel<<<(NN + 63) / 64, 256, 0, stream>>>(x, WPH, WPL, pre_b, FLAG, H);

    int nblk = (NN + 63) / 64;
    for (int l = 0; l < 3; ++l) {
        agg_kernel<<<NN / 4, 256, 0, stream>>>(H, EDGE, OFF, S);
        if (l < 2)
            gemm_relu<<<nblk, 256, 0, stream>>>(S, WFH + l * 12288, WFL + l * 12288, B[l], FLAG, H);
        else
            gemm_norm<<<nblk, 256, 0, stream>>>(S, WFH + l * 12288, WFL + l * 12288, B[l], FLAG, d_out);
    }
}

// Round 12
// 278.186 us; speedup vs baseline: 1.5020x; 1.1429x over previous
//
#include <hip/hip_runtime.h>
#include <hip/hip_bf16.h>

#define NN 50000
#define NE 800000
#define IND 128
#define C 64       // FEAT = HID = OUT
#define NBUCK 196  // coarse buckets of 256 nodes: 196*256 = 50176 >= NN

typedef __hip_bfloat16 bf16;
typedef __attribute__((ext_vector_type(8))) short s8v;    // 8 bf16 (4 VGPRs)
typedef __attribute__((ext_vector_type(4))) float f4v;    // MFMA C/D

__device__ __forceinline__ float to_f(float v) { return v; }
__device__ __forceinline__ float to_f(bf16 v)  { return __bfloat162float(v); }

__device__ __forceinline__ unsigned short f2b(float v) {
    unsigned u = __float_as_uint(v);
    return (unsigned short)((u + 0x7FFFu + ((u >> 16) & 1u)) >> 16);   // RNE
}
__device__ __forceinline__ float b2f(unsigned short u) {
    return __uint_as_float((unsigned)u << 16);
}

// --- dtype detect: float inputs fp32 (flag=1) or bf16 (flag=0)? ------------
__global__ void detect_kernel(const unsigned* __restrict__ xu, int* __restrict__ flag) {
    int lane = threadIdx.x;
    unsigned u  = xu[lane];
    unsigned ex = (u >> 7) & 0xFF;
    int vote = (ex >= 90 && ex <= 144) ? 1 : 0;
#pragma unroll
    for (int off = 32; off; off >>= 1) vote += __shfl_xor(vote, off, 64);
    if (lane == 0) *flag = (vote < 40) ? 1 : 0;
}

// --- fused: weight-fragment prep (blocks 0..175) + bucket count (176..566) -
// wprep: idx=((ct*nT+t)*64+lane)*8+j ; k=32t+(lane>>4)*8+j ; col=16ct+(lane&15)
// layout: pre at [0,8192), layer l at 8192+l*12288. (maps verified r10/r11)
__global__ __launch_bounds__(256) void prep_kernel(const void* pw, const void* w0,
        const void* w1, const void* w2, const int* __restrict__ flagp,
        const int* __restrict__ tgt,
        unsigned short* __restrict__ oh, unsigned short* __restrict__ ol,
        int* __restrict__ bcnt) {
    __shared__ int lc[NBUCK];
    int blk = blockIdx.x;
    int tid = threadIdx.x;
    if (blk < 176) {
        int gid = blk * 256 + tid;   // 45056 = 176*256 exactly
        const void* w; int nT, idx, base;
        if (gid < 8192) { w = pw; nT = 4; idx = gid; base = 0; }
        else {
            int r = gid - 8192; int l = r / 12288; idx = r % 12288; nT = 6;
            w = (l == 0) ? w0 : (l == 1) ? w1 : w2; base = 8192 + l * 12288;
        }
        int j = idx & 7, lane = (idx >> 3) & 63, r2 = idx >> 9;
        int t = r2 % nT, ct = r2 / nT;
        int k = 32 * t + ((lane >> 4) << 3) + j;
        int col = 16 * ct + (lane & 15);
        if (*flagp) {
            float v = ((const float*)w)[k * 64 + col];
            unsigned short hi = f2b(v);
            oh[base + idx] = hi;
            ol[base + idx] = f2b(v - b2f(hi));
        } else {
            oh[base + idx] = ((const unsigned short*)w)[k * 64 + col];
        }
    } else {
        for (int i = tid; i < NBUCK; i += 256) lc[i] = 0;
        __syncthreads();
        int e0 = (blk - 176) * 2048;
#pragma unroll
        for (int k = 0; k < 8; ++k) {
            int e = e0 + (k << 8) + tid;
            if (e < NE) atomicAdd(&lc[tgt[e] >> 8], 1);
        }
        __syncthreads();
        for (int i = tid; i < NBUCK; i += 256) if (lc[i]) atomicAdd(&bcnt[i], lc[i]);
    }
}

// --- bucket scan: 1 block, exclusive scan of 196 bucket counts -------------
__global__ __launch_bounds__(256) void bscan_kernel(const int* __restrict__ bcnt,
                                                    int* __restrict__ boff,
                                                    int* __restrict__ off) {
    __shared__ int wsum[4];
    int tid = threadIdx.x, lane = tid & 63, wv = tid >> 6;
    int v = (tid < NBUCK) ? bcnt[tid] : 0;
    int incl = v;
#pragma unroll
    for (int d = 1; d < 64; d <<= 1) { int t = __shfl_up(incl, d, 64); if (lane >= d) incl += t; }
    if (lane == 63) wsum[wv] = incl;
    __syncthreads();
    int wbase = 0;
#pragma unroll
    for (int j = 0; j < 4; ++j) wbase += (j < wv) ? wsum[j] : 0;
    if (tid < NBUCK) boff[tid] = wbase + incl - v;
    if (tid == 0) { boff[NBUCK] = NE; off[NN] = NE; }
}

// --- binA: block-local LDS histogram + clustered append into staging -------
template <typename T>
__device__ __forceinline__ void binA_impl(int* lcnt, int* lbase,
                                          const int* __restrict__ src,
                                          const int* __restrict__ tgt,
                                          const T* __restrict__ ea,
                                          const int* __restrict__ boff,
                                          int* __restrict__ ccur,
                                          float4* __restrict__ stg) {
    int tid = threadIdx.x;
    for (int i = tid; i < NBUCK; i += 256) lcnt[i] = 0;
    __syncthreads();
    int e0 = blockIdx.x * 2048;
    float ex[8], ey[8], ez[8];
    unsigned ew[8];
    int eb[8], er[8];
#pragma unroll
    for (int k = 0; k < 8; ++k) {
        int e = e0 + (k << 8) + tid;
        if (e < NE) {
            int t = tgt[e];
            int s = src[e];
            eb[k] = t >> 8;
            ew[k] = ((unsigned)t << 16) | (unsigned)s;
            ex[k] = to_f(ea[e * 3 + 0]);
            ey[k] = to_f(ea[e * 3 + 1]);
            ez[k] = to_f(ea[e * 3 + 2]);
            er[k] = atomicAdd(&lcnt[eb[k]], 1);
        } else eb[k] = -1;
    }
    __syncthreads();
    for (int i = tid; i < NBUCK; i += 256) {
        int c = lcnt[i];
        int g = c ? atomicAdd(&ccur[i], c) : 0;
        lbase[i] = boff[i] + g;
    }
    __syncthreads();
#pragma unroll
    for (int k = 0; k < 8; ++k) {
        if (eb[k] >= 0) {
            float4 r;
            r.x = ex[k]; r.y = ey[k]; r.z = ez[k];
            r.w = __uint_as_float(ew[k]);
            stg[lbase[eb[k]] + er[k]] = r;
        }
    }
}

__global__ __launch_bounds__(256) void binA_kernel(const int* __restrict__ src,
                                                   const int* __restrict__ tgt,
                                                   const void* ea,
                                                   const int* __restrict__ boff,
                                                   const int* __restrict__ flagp,
                                                   int* __restrict__ ccur,
                                                   float4* __restrict__ stg) {
    __shared__ int lcnt[NBUCK];
    __shared__ int lbase[NBUCK];
    if (*flagp) binA_impl<float>(lcnt, lbase, src, tgt, (const float*)ea, boff, ccur, stg);
    else        binA_impl<bf16>(lcnt, lbase, src, tgt, (const bf16*)ea, boff, ccur, stg);
}

// --- preM body (shared by fused kernel): h = x @ pre_w + pre_b -------------
template <typename T>
__device__ __forceinline__ void preM_body(int nb, const T* __restrict__ x,
                                          const unsigned short* __restrict__ wfh,
                                          const unsigned short* __restrict__ wfl,
                                          const T* __restrict__ b,
                                          unsigned short* __restrict__ h) {
    int tid = threadIdx.x;
    int lane = tid & 63, wv = tid >> 6;
    int m = lane & 15, g = lane >> 4;
    int arow = nb + wv * 16 + m;
    bool okrow = arow < NN;
    f4v acc[4] = {};
    for (int t = 0; t < 4; ++t) {
        if constexpr (sizeof(T) == 4) {
            float av[8];
            if (okrow) {
                const float* xr = (const float*)x + (size_t)arow * IND + t * 32 + g * 8;
                float4 v0 = *(const float4*)xr;
                float4 v1 = *(const float4*)(xr + 4);
                av[0] = v0.x; av[1] = v0.y; av[2] = v0.z; av[3] = v0.w;
                av[4] = v1.x; av[5] = v1.y; av[6] = v1.z; av[7] = v1.w;
            } else {
#pragma unroll
                for (int j = 0; j < 8; ++j) av[j] = 0.f;
            }
            s8v ahi, alo;
#pragma unroll
            for (int j = 0; j < 8; ++j) {
                unsigned short hi = f2b(av[j]);
                ahi[j] = (short)hi;
                alo[j] = (short)f2b(av[j] - b2f(hi));
            }
#pragma unroll
            for (int ct = 0; ct < 4; ++ct) {
                int fo = ((ct * 4 + t) * 64 + lane) * 8;
                s8v bh = *(const s8v*)&wfh[fo];
                s8v bl = *(const s8v*)&wfl[fo];
                acc[ct] = __builtin_amdgcn_mfma_f32_16x16x32_bf16(ahi, bh, acc[ct], 0, 0, 0);
                acc[ct] = __builtin_amdgcn_mfma_f32_16x16x32_bf16(alo, bh, acc[ct], 0, 0, 0);
                acc[ct] = __builtin_amdgcn_mfma_f32_16x16x32_bf16(ahi, bl, acc[ct], 0, 0, 0);
            }
        } else {
            s8v ahi = {};
            if (okrow)
                ahi = *(const s8v*)((const unsigned short*)x + (size_t)arow * IND + t * 32 + g * 8);
#pragma unroll
            for (int ct = 0; ct < 4; ++ct) {
                int fo = ((ct * 4 + t) * 64 + lane) * 8;
                s8v bh = *(const s8v*)&wfh[fo];
                acc[ct] = __builtin_amdgcn_mfma_f32_16x16x32_bf16(ahi, bh, acc[ct], 0, 0, 0);
            }
        }
    }
#pragma unroll
    for (int r = 0; r < 4; ++r) {
        int drow = nb + wv * 16 + g * 4 + r;
        if (drow < NN) {
#pragma unroll
            for (int ct = 0; ct < 4; ++ct)
                h[(size_t)drow * C + 16 * ct + m] = f2b(acc[ct][r] + to_f(b[16 * ct + m]));
        }
    }
}

// --- fused: binB (blocks 0..195: OFF build + final scatter) + preM ---------
__global__ __launch_bounds__(256) void binB_pre_kernel(const float4* __restrict__ stg,
        const int* __restrict__ boff, int* __restrict__ off, float4* __restrict__ edge,
        const void* x, const unsigned short* __restrict__ wfh,
        const unsigned short* __restrict__ wfl, const void* pb,
        const int* __restrict__ flagp, unsigned short* __restrict__ h) {
    __shared__ int lcnt[256];
    __shared__ int lexcl[256];
    __shared__ int lfill[256];
    __shared__ int wsum[4];
    int tid = threadIdx.x;
    if (blockIdx.x < NBUCK) {
        int b = blockIdx.x;
        int n0 = b << 8;
        int cb = boff[b], ce = boff[b + 1];
        lcnt[tid] = 0;
        __syncthreads();
        for (int i = cb + tid; i < ce; i += 256) {
            unsigned w = __float_as_uint(stg[i].w);
            atomicAdd(&lcnt[(w >> 16) & 255], 1);
        }
        __syncthreads();
        int lane = tid & 63, wv = tid >> 6;
        int v = lcnt[tid];
        int incl = v;
#pragma unroll
        for (int d = 1; d < 64; d <<= 1) { int t = __shfl_up(incl, d, 64); if (lane >= d) incl += t; }
        if (lane == 63) wsum[wv] = incl;
        __syncthreads();
        int wbase = 0;
#pragma unroll
        for (int j = 0; j < 4; ++j) wbase += (j < wv) ? wsum[j] : 0;
        lexcl[tid] = wbase + incl - v;
        lfill[tid] = 0;
        __syncthreads();
        int n = n0 + tid;
        if (n <= NN) off[n] = cb + lexcl[tid];
        for (int i = cb + tid; i < ce; i += 256) {
            float4 r = stg[i];
            unsigned w = __float_as_uint(r.w);
            int l = (int)(w >> 16) & 255;
            int rk = atomicAdd(&lfill[l], 1);
            r.w = __uint_as_float(w & 0xFFFFu);
            edge[cb + lexcl[l] + rk] = r;
        }
    } else {
        int nb = (blockIdx.x - NBUCK) * 64;
        if (*flagp) preM_body<float>(nb, (const float*)x, wfh, wfl, (const float*)pb, h);
        else        preM_body<bf16>(nb, (const bf16*)x, wfh, wfl, (const bf16*)pb, h);
    }
}

// --- aggregation: one wave/node, pipelined; writes split-bf16 S planes -----
__global__ __launch_bounds__(256) void agg_kernel(const unsigned short* __restrict__ hb,
                                                  const float4* __restrict__ edge,
                                                  const int* __restrict__ off,
                                                  unsigned short* __restrict__ sh,
                                                  unsigned short* __restrict__ sl) {
    int f = threadIdx.x & 63;
    int n = blockIdx.x * 4 + (threadIdx.x >> 6);
    int beg = __builtin_amdgcn_readfirstlane(off[n]);
    int end = __builtin_amdgcn_readfirstlane(off[n + 1]);
    float a0 = 0.f, a1 = 0.f, a2 = 0.f;
    int cnt = end - beg;
    int m4 = beg + (cnt & ~3);
    int e = beg;
    if (beg + 8 <= m4) {
        float4 c0 = edge[e],     c1 = edge[e + 1], c2 = edge[e + 2], c3 = edge[e + 3];
        float4 d0 = edge[e + 4], d1 = edge[e + 5], d2 = edge[e + 6], d3 = edge[e + 7];
        float h0 = b2f(hb[(__float_as_int(c0.w) << 6) + f]);
        float h1 = b2f(hb[(__float_as_int(c1.w) << 6) + f]);
        float h2 = b2f(hb[(__float_as_int(c2.w) << 6) + f]);
        float h3 = b2f(hb[(__float_as_int(c3.w) << 6) + f]);
        int e2 = beg + 8;
        while (e2 < m4) {
            float g0 = b2f(hb[(__float_as_int(d0.w) << 6) + f]);
            float g1 = b2f(hb[(__float_as_int(d1.w) << 6) + f]);
            float g2 = b2f(hb[(__float_as_int(d2.w) << 6) + f]);
            float g3 = b2f(hb[(__float_as_int(d3.w) << 6) + f]);
            float4 n0 = edge[e2], n1 = edge[e2 + 1], n2 = edge[e2 + 2], n3 = edge[e2 + 3];
            a0 += c0.x * h0; a1 += c0.y * h0; a2 += c0.z * h0;
            a0 += c1.x * h1; a1 += c1.y * h1; a2 += c1.z * h1;
            a0 += c2.x * h2; a1 += c2.y * h2; a2 += c2.z * h2;
            a0 += c3.x * h3; a1 += c3.y * h3; a2 += c3.z * h3;
            c0 = d0; c1 = d1; c2 = d2; c3 = d3;
            h0 = g0; h1 = g1; h2 = g2; h3 = g3;
            d0 = n0; d1 = n1; d2 = n2; d3 = n3;
            e2 += 4;
        }
        float g0 = b2f(hb[(__float_as_int(d0.w) << 6) + f]);
        float g1 = b2f(hb[(__float_as_int(d1.w) << 6) + f]);
        float g2 = b2f(hb[(__float_as_int(d2.w) << 6) + f]);
        float g3 = b2f(hb[(__float_as_int(d3.w) << 6) + f]);
        a0 += c0.x * h0; a1 += c0.y * h0; a2 += c0.z * h0;
        a0 += c1.x * h1; a1 += c1.y * h1; a2 += c1.z * h1;
        a0 += c2.x * h2; a1 += c2.y * h2; a2 += c2.z * h2;
        a0 += c3.x * h3; a1 += c3.y * h3; a2 += c3.z * h3;
        a0 += d0.x * g0; a1 += d0.y * g0; a2 += d0.z * g0;
        a0 += d1.x * g1; a1 += d1.y * g1; a2 += d1.z * g1;
        a0 += d2.x * g2; a1 += d2.y * g2; a2 += d2.z * g2;
        a0 += d3.x * g3; a1 += d3.y * g3; a2 += d3.z * g3;
        e = m4;
    } else if (beg + 4 <= m4) {
        float4 c0 = edge[e], c1 = edge[e + 1], c2 = edge[e + 2], c3 = edge[e + 3];
        float h0 = b2f(hb[(__float_as_int(c0.w) << 6) + f]);
        float h1 = b2f(hb[(__float_as_int(c1.w) << 6) + f]);
        float h2 = b2f(hb[(__float_as_int(c2.w) << 6) + f]);
        float h3 = b2f(hb[(__float_as_int(c3.w) << 6) + f]);
        a0 += c0.x * h0; a1 += c0.y * h0; a2 += c0.z * h0;
        a0 += c1.x * h1; a1 += c1.y * h1; a2 += c1.z * h1;
        a0 += c2.x * h2; a1 += c2.y * h2; a2 += c2.z * h2;
        a0 += c3.x * h3; a1 += c3.y * h3; a2 += c3.z * h3;
        e = m4;
    }
    for (; e < end; ++e) {
        float4 r = edge[e];
        float hv = b2f(hb[(__float_as_int(r.w) << 6) + f]);
        a0 += r.x * hv; a1 += r.y * hv; a2 += r.z * hv;
    }
    float iv = 1.0f / fmaxf((float)cnt, 1.0f);
    size_t base = (size_t)n * 192;
    float v0 = a0 * iv, v1 = a1 * iv, v2 = a2 * iv;
    unsigned short x0 = f2b(v0), x1 = f2b(v1), x2 = f2b(v2);
    sh[base + f]       = x0; sl[base + f]       = f2b(v0 - b2f(x0));
    sh[base + 64 + f]  = x1; sl[base + 64 + f]  = f2b(v1 - b2f(x1));
    sh[base + 128 + f] = x2; sl[base + 128 + f] = f2b(v2 - b2f(x2));
}

// --- dense via MFMA, A-fragments pre-split in SH/SL (no VALU convert) ------
// C/D mapping (m89-verified): col = lane&15, row = (lane>>4)*4 + reg.
// MODE 0: relu -> hout (bf16); MODE 1: L2-normalize -> out (T)
template <typename T, int MODE>
__device__ __forceinline__ void gemmM_impl(const unsigned short* __restrict__ sh,
                                           const unsigned short* __restrict__ sl,
                                           const unsigned short* __restrict__ wfh,
                                           const unsigned short* __restrict__ wfl,
                                           const T* __restrict__ b,
                                           unsigned short* __restrict__ hout, T* __restrict__ out) {
    int tid = threadIdx.x;
    int nb  = blockIdx.x * 64;
    int lane = tid & 63, wv = tid >> 6;
    int m = lane & 15, g = lane >> 4;
    int arow = nb + wv * 16 + m;
    bool okrow = arow < NN;
    const unsigned short* shrow = sh + (size_t)arow * 192 + g * 8;
    const unsigned short* slrow = sl + (size_t)arow * 192 + g * 8;
    f4v acc[4] = {};
    for (int t = 0; t < 6; ++t) {
        s8v ahi = {}, alo = {};
        if (okrow) {
            ahi = *(const s8v*)(shrow + t * 32);
            alo = *(const s8v*)(slrow + t * 32);
        }
#pragma unroll
        for (int ct = 0; ct < 4; ++ct) {
            int fo = ((ct * 6 + t) * 64 + lane) * 8;
            s8v bh = *(const s8v*)&wfh[fo];
            acc[ct] = __builtin_amdgcn_mfma_f32_16x16x32_bf16(ahi, bh, acc[ct], 0, 0, 0);
            acc[ct] = __builtin_amdgcn_mfma_f32_16x16x32_bf16(alo, bh, acc[ct], 0, 0, 0);
            if constexpr (sizeof(T) == 4) {
                s8v bl = *(const s8v*)&wfl[fo];
                acc[ct] = __builtin_amdgcn_mfma_f32_16x16x32_bf16(ahi, bl, acc[ct], 0, 0, 0);
            }
        }
    }
    float vv[4][4];
#pragma unroll
    for (int ct = 0; ct < 4; ++ct) {
        float bv = to_f(b[16 * ct + m]);
#pragma unroll
        for (int r = 0; r < 4; ++r) vv[ct][r] = acc[ct][r] + bv;
    }
    if constexpr (MODE == 0) {
#pragma unroll
        for (int r = 0; r < 4; ++r) {
            int drow = nb + wv * 16 + g * 4 + r;
            if (drow < NN) {
#pragma unroll
                for (int ct = 0; ct < 4; ++ct)
                    hout[(size_t)drow * C + 16 * ct + m] = f2b(fmaxf(vv[ct][r], 0.f));
            }
        }
    } else {
#pragma unroll
        for (int r = 0; r < 4; ++r) {
            float sq = vv[0][r] * vv[0][r] + vv[1][r] * vv[1][r]
                     + vv[2][r] * vv[2][r] + vv[3][r] * vv[3][r];
#pragma unroll
            for (int o = 1; o < 16; o <<= 1) sq += __shfl_xor(sq, o, 64);
            float innorm = 1.0f / fmaxf(sqrtf(sq), 1e-12f);
            int drow = nb + wv * 16 + g * 4 + r;
            if (drow < NN) {
#pragma unroll
                for (int ct = 0; ct < 4; ++ct) {
                    float rv = vv[ct][r] * innorm;
                    if constexpr (sizeof(T) == 2) out[(size_t)drow * C + 16 * ct + m] = __float2bfloat16(rv);
                    else                          out[(size_t)drow * C + 16 * ct + m] = rv;
                }
            }
        }
    }
}

__global__ __launch_bounds__(256) void gemm_relu(const unsigned short* __restrict__ sh,
                                                 const unsigned short* __restrict__ sl,
                                                 const unsigned short* __restrict__ wfh,
                                                 const unsigned short* __restrict__ wfl,
                                                 const void* b, const int* __restrict__ flagp,
                                                 unsigned short* __restrict__ hout) {
    if (*flagp) gemmM_impl<float, 0>(sh, sl, wfh, wfl, (const float*)b, hout, (float*)nullptr);
    else        gemmM_impl<bf16, 0>(sh, sl, wfh, wfl, (const bf16*)b, hout, (bf16*)nullptr);
}

__global__ __launch_bounds__(256) void gemm_norm(const unsigned short* __restrict__ sh,
                                                 const unsigned short* __restrict__ sl,
                                                 const unsigned short* __restrict__ wfh,
                                                 const unsigned short* __restrict__ wfl,
                                                 const void* b, const int* __restrict__ flagp,
                                                 void* out) {
    if (*flagp) gemmM_impl<float, 1>(sh, sl, wfh, wfl, (const float*)b, nullptr, (float*)out);
    else        gemmM_impl<bf16, 1>(sh, sl, wfh, wfl, (const bf16*)b, nullptr, (bf16*)out);
}

extern "C" void kernel_launch(void* const* d_in, const int* in_sizes, int n_in,
                              void* d_out, int out_size, void* d_ws, size_t ws_size,
                              hipStream_t stream) {
    const void* x     = d_in[0];
    const int*  ei    = (const int*)d_in[1];
    const void* ea    = d_in[2];
    const void* pre_w = d_in[3];
    const void* pre_b = d_in[4];
    const void* W[3]  = {d_in[5], d_in[7], d_in[9]};
    const void* B[3]  = {d_in[6], d_in[8], d_in[10]};
    const int* src = ei;
    const int* tgt = ei + NE;

    // ws: EDGE f4[NE] | SH u16[NN*192] (STG overlays) | SL u16[NN*192]
    //     | H u16[NN*64] | BCNT[256] CCUR[256] BOFF[256] OFF[NN+8] FLAG[16]
    //     | WH u16[45056] WL u16[45056]
    float4*         EDGE = (float4*)d_ws;                            // 12.8 MB
    unsigned short* SH   = (unsigned short*)(EDGE + NE);             // 19.2 MB
    unsigned short* SL   = SH + (size_t)NN * 192;                    // 19.2 MB
    float4*         STG  = (float4*)SH;                              // overlay (12.8 MB)
    unsigned short* H    = SL + (size_t)NN * 192;                    // 6.4 MB
    int*            BCNT = (int*)(H + (size_t)NN * C);
    int*            CCUR = BCNT + 256;
    int*            BOFF = CCUR + 256;
    int*            OFF  = BOFF + 256;
    int*            FLAG = OFF + NN + 8;
    unsigned short* WH   = (unsigned short*)(FLAG + 16);  // pre@0, W[l]@8192+l*12288
    unsigned short* WL   = WH + 45056;

    hipMemsetAsync(BCNT, 0, 512 * sizeof(int), stream);   // BCNT + CCUR
    detect_kernel<<<1, 64, 0, stream>>>((const unsigned*)x, FLAG);
    prep_kernel<<<176 + (NE + 2047) / 2048, 256, 0, stream>>>(pre_w, W[0], W[1], W[2],
                                                              FLAG, tgt, WH, WL, BCNT);
    bscan_kernel<<<1, 256, 0, stream>>>(BCNT, BOFF, OFF);
    binA_kernel<<<(NE + 2047) / 2048, 256, 0, stream>>>(src, tgt, ea, BOFF, FLAG, CCUR, STG);
    binB_pre_kernel<<<NBUCK + (NN + 63) / 64, 256, 0, stream>>>(STG, BOFF, OFF, EDGE,
                                                                x, WH, WL, pre_b, FLAG, H);

    int nblk = (NN + 63) / 64;
    for (int l = 0; l < 3; ++l) {
        const unsigned short* wfh = WH + 8192 + l * 12288;
        const unsigned short* wfl = WL + 8192 + l * 12288;
        agg_kernel<<<NN / 4, 256, 0, stream>>>(H, EDGE, OFF, SH, SL);
        if (l < 2)
            gemm_relu<<<nblk, 256, 0, stream>>>(SH, SL, wfh, wfl, B[l], FLAG, H);
        else
            gemm_norm<<<nblk, 256, 0, stream>>>(SH, SL, wfh, wfl, B[l], FLAG, d_out);
    }
}

// Round 13
// 275.550 us; speedup vs baseline: 1.5164x; 1.0096x over previous
//
#include <hip/hip_runtime.h>
#include <hip/hip_bf16.h>

#define NN 50000
#define NE 800000
#define IND 128
#define C 64       // FEAT = HID = OUT
#define NBUCK 196  // coarse buckets of 256 nodes: 196*256 = 50176 >= NN

typedef __hip_bfloat16 bf16;
typedef __attribute__((ext_vector_type(8))) short s8v;    // 8 bf16 (4 VGPRs)
typedef __attribute__((ext_vector_type(4))) float f4v;    // MFMA C/D

__device__ __forceinline__ float to_f(float v) { return v; }
__device__ __forceinline__ float to_f(bf16 v)  { return __bfloat162float(v); }

__device__ __forceinline__ unsigned short f2b(float v) {
    unsigned u = __float_as_uint(v);
    return (unsigned short)((u + 0x7FFFu + ((u >> 16) & 1u)) >> 16);   // RNE
}
__device__ __forceinline__ float b2f(unsigned short u) {
    return __uint_as_float((unsigned)u << 16);
}

// --- dtype detect + zero BCNT/CCUR/ARR (replaces hipMemsetAsync) -----------
__global__ void detect_kernel(const unsigned* __restrict__ xu, int* __restrict__ flag,
                              int* __restrict__ zbase) {
    int lane = threadIdx.x;
    for (int i = lane; i < 512; i += 64) zbase[i] = 0;   // BCNT + CCUR
    unsigned u  = xu[lane];
    unsigned ex = (u >> 7) & 0xFF;
    int vote = (ex >= 90 && ex <= 144) ? 1 : 0;
#pragma unroll
    for (int off = 32; off; off >>= 1) vote += __shfl_xor(vote, off, 64);
    if (lane == 0) { flag[0] = (vote < 40) ? 1 : 0; flag[1] = 0; }   // flag[1] = arrival
}

// --- fused: weight-fragment prep (blocks 0..175) + bucket count (176..) ----
// wprep: idx=((ct*nT+t)*64+lane)*8+j ; k=32t+(lane>>4)*8+j ; col=16ct+(lane&15)
// layout: pre at [0,8192), layer l at 8192+l*12288. (maps verified r10/r11)
// Last-arriving count block performs the 196-bucket exclusive scan (r13).
__global__ __launch_bounds__(256) void prep_kernel(const void* pw, const void* w0,
        const void* w1, const void* w2, int* __restrict__ flagp,
        const int* __restrict__ tgt,
        unsigned short* __restrict__ oh, unsigned short* __restrict__ ol,
        int* __restrict__ bcnt, int* __restrict__ boff, int* __restrict__ off) {
    __shared__ int lc[NBUCK];
    __shared__ int rank_s;
    __shared__ int wsum[4];
    int blk = blockIdx.x;
    int tid = threadIdx.x;
    if (blk < 176) {
        int gid = blk * 256 + tid;   // 45056 = 176*256 exactly
        const void* w; int nT, idx, base;
        if (gid < 8192) { w = pw; nT = 4; idx = gid; base = 0; }
        else {
            int r = gid - 8192; int l = r / 12288; idx = r % 12288; nT = 6;
            w = (l == 0) ? w0 : (l == 1) ? w1 : w2; base = 8192 + l * 12288;
        }
        int j = idx & 7, lane = (idx >> 3) & 63, r2 = idx >> 9;
        int t = r2 % nT, ct = r2 / nT;
        int k = 32 * t + ((lane >> 4) << 3) + j;
        int col = 16 * ct + (lane & 15);
        if (*flagp) {
            float v = ((const float*)w)[k * 64 + col];
            unsigned short hi = f2b(v);
            oh[base + idx] = hi;
            ol[base + idx] = f2b(v - b2f(hi));
        } else {
            oh[base + idx] = ((const unsigned short*)w)[k * 64 + col];
        }
        return;
    }
    // bucket count
    for (int i = tid; i < NBUCK; i += 256) lc[i] = 0;
    __syncthreads();
    int e0 = (blk - 176) * 2048;
#pragma unroll
    for (int k = 0; k < 8; ++k) {
        int e = e0 + (k << 8) + tid;
        if (e < NE) atomicAdd(&lc[tgt[e] >> 8], 1);
    }
    __syncthreads();
    for (int i = tid; i < NBUCK; i += 256) if (lc[i]) atomicAdd(&bcnt[i], lc[i]);
    __syncthreads();
    if (tid == 0) {
        __threadfence();
        rank_s = atomicAdd(&flagp[1], 1);   // arrival counter
    }
    __syncthreads();
    int nCnt = (int)gridDim.x - 176;
    if (rank_s == nCnt - 1) {
        // last count block: exclusive scan bcnt[0..195] -> boff
        int lane = tid & 63, wv = tid >> 6;
        int v = (tid < NBUCK) ? atomicAdd(&bcnt[tid], 0) : 0;   // coherent read
        int incl = v;
#pragma unroll
        for (int d = 1; d < 64; d <<= 1) { int t = __shfl_up(incl, d, 64); if (lane >= d) incl += t; }
        if (lane == 63) wsum[wv] = incl;
        __syncthreads();
        int wbase = 0;
#pragma unroll
        for (int j = 0; j < 4; ++j) wbase += (j < wv) ? wsum[j] : 0;
        if (tid < NBUCK) boff[tid] = wbase + incl - v;
        if (tid == 0) { boff[NBUCK] = NE; off[NN] = NE; }
    }
}

// --- binA: block-local LDS histogram + clustered append into staging -------
template <typename T>
__device__ __forceinline__ void binA_impl(int* lcnt, int* lbase,
                                          const int* __restrict__ src,
                                          const int* __restrict__ tgt,
                                          const T* __restrict__ ea,
                                          const int* __restrict__ boff,
                                          int* __restrict__ ccur,
                                          float4* __restrict__ stg) {
    int tid = threadIdx.x;
    for (int i = tid; i < NBUCK; i += 256) lcnt[i] = 0;
    __syncthreads();
    int e0 = blockIdx.x * 2048;
    float ex[8], ey[8], ez[8];
    unsigned ew[8];
    int eb[8], er[8];
#pragma unroll
    for (int k = 0; k < 8; ++k) {
        int e = e0 + (k << 8) + tid;
        if (e < NE) {
            int t = tgt[e];
            int s = src[e];
            eb[k] = t >> 8;
            ew[k] = ((unsigned)t << 16) | (unsigned)s;
            ex[k] = to_f(ea[e * 3 + 0]);
            ey[k] = to_f(ea[e * 3 + 1]);
            ez[k] = to_f(ea[e * 3 + 2]);
            er[k] = atomicAdd(&lcnt[eb[k]], 1);
        } else eb[k] = -1;
    }
    __syncthreads();
    for (int i = tid; i < NBUCK; i += 256) {
        int c = lcnt[i];
        int g = c ? atomicAdd(&ccur[i], c) : 0;
        lbase[i] = boff[i] + g;
    }
    __syncthreads();
#pragma unroll
    for (int k = 0; k < 8; ++k) {
        if (eb[k] >= 0) {
            float4 r;
            r.x = ex[k]; r.y = ey[k]; r.z = ez[k];
            r.w = __uint_as_float(ew[k]);
            stg[lbase[eb[k]] + er[k]] = r;
        }
    }
}

__global__ __launch_bounds__(256) void binA_kernel(const int* __restrict__ src,
                                                   const int* __restrict__ tgt,
                                                   const void* ea,
                                                   const int* __restrict__ boff,
                                                   const int* __restrict__ flagp,
                                                   int* __restrict__ ccur,
                                                   float4* __restrict__ stg) {
    __shared__ int lcnt[NBUCK];
    __shared__ int lbase[NBUCK];
    if (*flagp) binA_impl<float>(lcnt, lbase, src, tgt, (const float*)ea, boff, ccur, stg);
    else        binA_impl<bf16>(lcnt, lbase, src, tgt, (const bf16*)ea, boff, ccur, stg);
}

// --- preM body (shared by fused kernel): h = x @ pre_w + pre_b -------------
template <typename T>
__device__ __forceinline__ void preM_body(int nb, const T* __restrict__ x,
                                          const unsigned short* __restrict__ wfh,
                                          const unsigned short* __restrict__ wfl,
                                          const T* __restrict__ b,
                                          unsigned short* __restrict__ h) {
    int tid = threadIdx.x;
    int lane = tid & 63, wv = tid >> 6;
    int m = lane & 15, g = lane >> 4;
    int arow = nb + wv * 16 + m;
    bool okrow = arow < NN;
    f4v acc[4] = {};
    for (int t = 0; t < 4; ++t) {
        if constexpr (sizeof(T) == 4) {
            float av[8];
            if (okrow) {
                const float* xr = (const float*)x + (size_t)arow * IND + t * 32 + g * 8;
                float4 v0 = *(const float4*)xr;
                float4 v1 = *(const float4*)(xr + 4);
                av[0] = v0.x; av[1] = v0.y; av[2] = v0.z; av[3] = v0.w;
                av[4] = v1.x; av[5] = v1.y; av[6] = v1.z; av[7] = v1.w;
            } else {
#pragma unroll
                for (int j = 0; j < 8; ++j) av[j] = 0.f;
            }
            s8v ahi, alo;
#pragma unroll
            for (int j = 0; j < 8; ++j) {
                unsigned short hi = f2b(av[j]);
                ahi[j] = (short)hi;
                alo[j] = (short)f2b(av[j] - b2f(hi));
            }
#pragma unroll
            for (int ct = 0; ct < 4; ++ct) {
                int fo = ((ct * 4 + t) * 64 + lane) * 8;
                s8v bh = *(const s8v*)&wfh[fo];
                s8v bl = *(const s8v*)&wfl[fo];
                acc[ct] = __builtin_amdgcn_mfma_f32_16x16x32_bf16(ahi, bh, acc[ct], 0, 0, 0);
                acc[ct] = __builtin_amdgcn_mfma_f32_16x16x32_bf16(alo, bh, acc[ct], 0, 0, 0);
                acc[ct] = __builtin_amdgcn_mfma_f32_16x16x32_bf16(ahi, bl, acc[ct], 0, 0, 0);
            }
        } else {
            s8v ahi = {};
            if (okrow)
                ahi = *(const s8v*)((const unsigned short*)x + (size_t)arow * IND + t * 32 + g * 8);
#pragma unroll
            for (int ct = 0; ct < 4; ++ct) {
                int fo = ((ct * 4 + t) * 64 + lane) * 8;
                s8v bh = *(const s8v*)&wfh[fo];
                acc[ct] = __builtin_amdgcn_mfma_f32_16x16x32_bf16(ahi, bh, acc[ct], 0, 0, 0);
            }
        }
    }
#pragma unroll
    for (int r = 0; r < 4; ++r) {
        int drow = nb + wv * 16 + g * 4 + r;
        if (drow < NN) {
#pragma unroll
            for (int ct = 0; ct < 4; ++ct)
                h[(size_t)drow * C + 16 * ct + m] = f2b(acc[ct][r] + to_f(b[16 * ct + m]));
        }
    }
}

// --- fused: binB (blocks 0..195: OFF build + final scatter) + preM ---------
__global__ __launch_bounds__(256) void binB_pre_kernel(const float4* __restrict__ stg,
        const int* __restrict__ boff, int* __restrict__ off, float4* __restrict__ edge,
        const void* x, const unsigned short* __restrict__ wfh,
        const unsigned short* __restrict__ wfl, const void* pb,
        const int* __restrict__ flagp, unsigned short* __restrict__ h) {
    __shared__ int lcnt[256];
    __shared__ int lexcl[256];
    __shared__ int lfill[256];
    __shared__ int wsum[4];
    int tid = threadIdx.x;
    if (blockIdx.x < NBUCK) {
        int b = blockIdx.x;
        int n0 = b << 8;
        int cb = boff[b], ce = boff[b + 1];
        lcnt[tid] = 0;
        __syncthreads();
        for (int i = cb + tid; i < ce; i += 256) {
            unsigned w = __float_as_uint(stg[i].w);
            atomicAdd(&lcnt[(w >> 16) & 255], 1);
        }
        __syncthreads();
        int lane = tid & 63, wv = tid >> 6;
        int v = lcnt[tid];
        int incl = v;
#pragma unroll
        for (int d = 1; d < 64; d <<= 1) { int t = __shfl_up(incl, d, 64); if (lane >= d) incl += t; }
        if (lane == 63) wsum[wv] = incl;
        __syncthreads();
        int wbase = 0;
#pragma unroll
        for (int j = 0; j < 4; ++j) wbase += (j < wv) ? wsum[j] : 0;
        lexcl[tid] = wbase + incl - v;
        lfill[tid] = 0;
        __syncthreads();
        int n = n0 + tid;
        if (n <= NN) off[n] = cb + lexcl[tid];
        for (int i = cb + tid; i < ce; i += 256) {
            float4 r = stg[i];
            unsigned w = __float_as_uint(r.w);
            int l = (int)(w >> 16) & 255;
            int rk = atomicAdd(&lfill[l], 1);
            r.w = __uint_as_float(w & 0xFFFFu);
            edge[cb + lexcl[l] + rk] = r;
        }
    } else {
        int nb = (blockIdx.x - NBUCK) * 64;
        if (*flagp) preM_body<float>(nb, (const float*)x, wfh, wfl, (const float*)pb, h);
        else        preM_body<bf16>(nb, (const bf16*)x, wfh, wfl, (const bf16*)pb, h);
    }
}

// --- aggregation: one wave/node, pipelined; writes split-bf16 S planes -----
__global__ __launch_bounds__(256) void agg_kernel(const unsigned short* __restrict__ hb,
                                                  const float4* __restrict__ edge,
                                                  const int* __restrict__ off,
                                                  unsigned short* __restrict__ sh,
                                                  unsigned short* __restrict__ sl) {
    int f = threadIdx.x & 63;
    int n = blockIdx.x * 4 + (threadIdx.x >> 6);
    int beg = __builtin_amdgcn_readfirstlane(off[n]);
    int end = __builtin_amdgcn_readfirstlane(off[n + 1]);
    float a0 = 0.f, a1 = 0.f, a2 = 0.f;
    int cnt = end - beg;
    int m4 = beg + (cnt & ~3);
    int e = beg;
    if (beg + 8 <= m4) {
        float4 c0 = edge[e],     c1 = edge[e + 1], c2 = edge[e + 2], c3 = edge[e + 3];
        float4 d0 = edge[e + 4], d1 = edge[e + 5], d2 = edge[e + 6], d3 = edge[e + 7];
        float h0 = b2f(hb[(__float_as_int(c0.w) << 6) + f]);
        float h1 = b2f(hb[(__float_as_int(c1.w) << 6) + f]);
        float h2 = b2f(hb[(__float_as_int(c2.w) << 6) + f]);
        float h3 = b2f(hb[(__float_as_int(c3.w) << 6) + f]);
        int e2 = beg + 8;
        while (e2 < m4) {
            float g0 = b2f(hb[(__float_as_int(d0.w) << 6) + f]);
            float g1 = b2f(hb[(__float_as_int(d1.w) << 6) + f]);
            float g2 = b2f(hb[(__float_as_int(d2.w) << 6) + f]);
            float g3 = b2f(hb[(__float_as_int(d3.w) << 6) + f]);
            float4 n0 = edge[e2], n1 = edge[e2 + 1], n2 = edge[e2 + 2], n3 = edge[e2 + 3];
            a0 += c0.x * h0; a1 += c0.y * h0; a2 += c0.z * h0;
            a0 += c1.x * h1; a1 += c1.y * h1; a2 += c1.z * h1;
            a0 += c2.x * h2; a1 += c2.y * h2; a2 += c2.z * h2;
            a0 += c3.x * h3; a1 += c3.y * h3; a2 += c3.z * h3;
            c0 = d0; c1 = d1; c2 = d2; c3 = d3;
            h0 = g0; h1 = g1; h2 = g2; h3 = g3;
            d0 = n0; d1 = n1; d2 = n2; d3 = n3;
            e2 += 4;
        }
        float g0 = b2f(hb[(__float_as_int(d0.w) << 6) + f]);
        float g1 = b2f(hb[(__float_as_int(d1.w) << 6) + f]);
        float g2 = b2f(hb[(__float_as_int(d2.w) << 6) + f]);
        float g3 = b2f(hb[(__float_as_int(d3.w) << 6) + f]);
        a0 += c0.x * h0; a1 += c0.y * h0; a2 += c0.z * h0;
        a0 += c1.x * h1; a1 += c1.y * h1; a2 += c1.z * h1;
        a0 += c2.x * h2; a1 += c2.y * h2; a2 += c2.z * h2;
        a0 += c3.x * h3; a1 += c3.y * h3; a2 += c3.z * h3;
        a0 += d0.x * g0; a1 += d0.y * g0; a2 += d0.z * g0;
        a0 += d1.x * g1; a1 += d1.y * g1; a2 += d1.z * g1;
        a0 += d2.x * g2; a1 += d2.y * g2; a2 += d2.z * g2;
        a0 += d3.x * g3; a1 += d3.y * g3; a2 += d3.z * g3;
        e = m4;
    } else if (beg + 4 <= m4) {
        float4 c0 = edge[e], c1 = edge[e + 1], c2 = edge[e + 2], c3 = edge[e + 3];
        float h0 = b2f(hb[(__float_as_int(c0.w) << 6) + f]);
        float h1 = b2f(hb[(__float_as_int(c1.w) << 6) + f]);
        float h2 = b2f(hb[(__float_as_int(c2.w) << 6) + f]);
        float h3 = b2f(hb[(__float_as_int(c3.w) << 6) + f]);
        a0 += c0.x * h0; a1 += c0.y * h0; a2 += c0.z * h0;
        a0 += c1.x * h1; a1 += c1.y * h1; a2 += c1.z * h1;
        a0 += c2.x * h2; a1 += c2.y * h2; a2 += c2.z * h2;
        a0 += c3.x * h3; a1 += c3.y * h3; a2 += c3.z * h3;
        e = m4;
    }
    for (; e < end; ++e) {
        float4 r = edge[e];
        float hv = b2f(hb[(__float_as_int(r.w) << 6) + f]);
        a0 += r.x * hv; a1 += r.y * hv; a2 += r.z * hv;
    }
    float iv = 1.0f / fmaxf((float)cnt, 1.0f);
    size_t base = (size_t)n * 192;
    float v0 = a0 * iv, v1 = a1 * iv, v2 = a2 * iv;
    unsigned short x0 = f2b(v0), x1 = f2b(v1), x2 = f2b(v2);
    sh[base + f]       = x0; sl[base + f]       = f2b(v0 - b2f(x0));
    sh[base + 64 + f]  = x1; sl[base + 64 + f]  = f2b(v1 - b2f(x1));
    sh[base + 128 + f] = x2; sl[base + 128 + f] = f2b(v2 - b2f(x2));
}

// --- dense via MFMA, A-fragments pre-split in SH/SL (no VALU convert) ------
// C/D mapping (m89-verified): col = lane&15, row = (lane>>4)*4 + reg.
// MODE 0: relu -> hout (bf16); MODE 1: L2-normalize -> out (T)
template <typename T, int MODE>
__device__ __forceinline__ void gemmM_impl(const unsigned short* __restrict__ sh,
                                           const unsigned short* __restrict__ sl,
                                           const unsigned short* __restrict__ wfh,
                                           const unsigned short* __restrict__ wfl,
                                           const T* __restrict__ b,
                                           unsigned short* __restrict__ hout, T* __restrict__ out) {
    int tid = threadIdx.x;
    int nb  = blockIdx.x * 64;
    int lane = tid & 63, wv = tid >> 6;
    int m = lane & 15, g = lane >> 4;
    int arow = nb + wv * 16 + m;
    bool okrow = arow < NN;
    const unsigned short* shrow = sh + (size_t)arow * 192 + g * 8;
    const unsigned short* slrow = sl + (size_t)arow * 192 + g * 8;
    f4v acc[4] = {};
    for (int t = 0; t < 6; ++t) {
        s8v ahi = {}, alo = {};
        if (okrow) {
            ahi = *(const s8v*)(shrow + t * 32);
            alo = *(const s8v*)(slrow + t * 32);
        }
#pragma unroll
        for (int ct = 0; ct < 4; ++ct) {
            int fo = ((ct * 6 + t) * 64 + lane) * 8;
            s8v bh = *(const s8v*)&wfh[fo];
            acc[ct] = __builtin_amdgcn_mfma_f32_16x16x32_bf16(ahi, bh, acc[ct], 0, 0, 0);
            acc[ct] = __builtin_amdgcn_mfma_f32_16x16x32_bf16(alo, bh, acc[ct], 0, 0, 0);
            if constexpr (sizeof(T) == 4) {
                s8v bl = *(const s8v*)&wfl[fo];
                acc[ct] = __builtin_amdgcn_mfma_f32_16x16x32_bf16(ahi, bl, acc[ct], 0, 0, 0);
            }
        }
    }
    float vv[4][4];
#pragma unroll
    for (int ct = 0; ct < 4; ++ct) {
        float bv = to_f(b[16 * ct + m]);
#pragma unroll
        for (int r = 0; r < 4; ++r) vv[ct][r] = acc[ct][r] + bv;
    }
    if constexpr (MODE == 0) {
#pragma unroll
        for (int r = 0; r < 4; ++r) {
            int drow = nb + wv * 16 + g * 4 + r;
            if (drow < NN) {
#pragma unroll
                for (int ct = 0; ct < 4; ++ct)
                    hout[(size_t)drow * C + 16 * ct + m] = f2b(fmaxf(vv[ct][r], 0.f));
            }
        }
    } else {
#pragma unroll
        for (int r = 0; r < 4; ++r) {
            float sq = vv[0][r] * vv[0][r] + vv[1][r] * vv[1][r]
                     + vv[2][r] * vv[2][r] + vv[3][r] * vv[3][r];
#pragma unroll
            for (int o = 1; o < 16; o <<= 1) sq += __shfl_xor(sq, o, 64);
            float innorm = 1.0f / fmaxf(sqrtf(sq), 1e-12f);
            int drow = nb + wv * 16 + g * 4 + r;
            if (drow < NN) {
#pragma unroll
                for (int ct = 0; ct < 4; ++ct) {
                    float rv = vv[ct][r] * innorm;
                    if constexpr (sizeof(T) == 2) out[(size_t)drow * C + 16 * ct + m] = __float2bfloat16(rv);
                    else                          out[(size_t)drow * C + 16 * ct + m] = rv;
                }
            }
        }
    }
}

__global__ __launch_bounds__(256) void gemm_relu(const unsigned short* __restrict__ sh,
                                                 const unsigned short* __restrict__ sl,
                                                 const unsigned short* __restrict__ wfh,
                                                 const unsigned short* __restrict__ wfl,
                                                 const void* b, const int* __restrict__ flagp,
                                                 unsigned short* __restrict__ hout) {
    if (*flagp) gemmM_impl<float, 0>(sh, sl, wfh, wfl, (const float*)b, hout, (float*)nullptr);
    else        gemmM_impl<bf16, 0>(sh, sl, wfh, wfl, (const bf16*)b, hout, (bf16*)nullptr);
}

__global__ __launch_bounds__(256) void gemm_norm(const unsigned short* __restrict__ sh,
                                                 const unsigned short* __restrict__ sl,
                                                 const unsigned short* __restrict__ wfh,
                                                 const unsigned short* __restrict__ wfl,
                                                 const void* b, const int* __restrict__ flagp,
                                                 void* out) {
    if (*flagp) gemmM_impl<float, 1>(sh, sl, wfh, wfl, (const float*)b, nullptr, (float*)out);
    else        gemmM_impl<bf16, 1>(sh, sl, wfh, wfl, (const bf16*)b, nullptr, (bf16*)out);
}

extern "C" void kernel_launch(void* const* d_in, const int* in_sizes, int n_in,
                              void* d_out, int out_size, void* d_ws, size_t ws_size,
                              hipStream_t stream) {
    const void* x     = d_in[0];
    const int*  ei    = (const int*)d_in[1];
    const void* ea    = d_in[2];
    const void* pre_w = d_in[3];
    const void* pre_b = d_in[4];
    const void* W[3]  = {d_in[5], d_in[7], d_in[9]};
    const void* B[3]  = {d_in[6], d_in[8], d_in[10]};
    const int* src = ei;
    const int* tgt = ei + NE;

    // ws: EDGE f4[NE] | SH u16[NN*192] (STG overlays) | SL u16[NN*192]
    //     | H u16[NN*64] | BCNT[256] CCUR[256] BOFF[256] OFF[NN+8] FLAG[16]
    //     | WH u16[45056] WL u16[45056]
    float4*         EDGE = (float4*)d_ws;                            // 12.8 MB
    unsigned short* SH   = (unsigned short*)(EDGE + NE);             // 19.2 MB
    unsigned short* SL   = SH + (size_t)NN * 192;                    // 19.2 MB
    float4*         STG  = (float4*)SH;                              // overlay (12.8 MB)
    unsigned short* H    = SL + (size_t)NN * 192;                    // 6.4 MB
    int*            BCNT = (int*)(H + (size_t)NN * C);
    int*            CCUR = BCNT + 256;
    int*            BOFF = CCUR + 256;
    int*            OFF  = BOFF + 256;
    int*            FLAG = OFF + NN + 8;   // FLAG[0]=dtype, FLAG[1]=arrival
    unsigned short* WH   = (unsigned short*)(FLAG + 16);  // pre@0, W[l]@8192+l*12288
    unsigned short* WL   = WH + 45056;

    detect_kernel<<<1, 64, 0, stream>>>((const unsigned*)x, FLAG, BCNT);
    prep_kernel<<<176 + (NE + 2047) / 2048, 256, 0, stream>>>(pre_w, W[0], W[1], W[2],
                                                              FLAG, tgt, WH, WL,
                                                              BCNT, BOFF, OFF);
    binA_kernel<<<(NE + 2047) / 2048, 256, 0, stream>>>(src, tgt, ea, BOFF, FLAG, CCUR, STG);
    binB_pre_kernel<<<NBUCK + (NN + 63) / 64, 256, 0, stream>>>(STG, BOFF, OFF, EDGE,
                                                                x, WH, WL, pre_b, FLAG, H);

    int nblk = (NN + 63) / 64;
    for (int l = 0; l < 3; ++l) {
        const unsigned short* wfh = WH + 8192 + l * 12288;
        const unsigned short* wfl = WL + 8192 + l * 12288;
        agg_kernel<<<NN / 4, 256, 0, stream>>>(H, EDGE, OFF, SH, SL);
        if (l < 2)
            gemm_relu<<<nblk, 256, 0, stream>>>(SH, SL, wfh, wfl, B[l], FLAG, H);
        else
            gemm_norm<<<nblk, 256, 0, stream>>>(SH, SL, wfh, wfl, B[l], FLAG, d_out);
    }
}